// Round 8
// baseline (774.414 us; speedup 1.0000x reference)
//
#include <hip/hip_runtime.h>

// ---------------- bf16 helpers ----------------

__device__ __forceinline__ unsigned short f2bf(float f) {
    unsigned u = __float_as_uint(f);
    unsigned r = (u + 0x7FFFu + ((u >> 16) & 1u)) >> 16;
    return (unsigned short)r;
}
__device__ __forceinline__ float bf2f(unsigned short u) {
    return __uint_as_float(((unsigned)u) << 16);
}

// ---------------- node GEMM + attention scores ----------------
// One 64-row tile per block. X tile staged in LDS via coalesced per-lane
// float4 loads. Each wave computes 16 rows as 4 groups of 4 FMA chains.
template<int K>
__global__ __launch_bounds__(256, 2)
void gat_gemm_kernel(const float* __restrict__ X, const float* __restrict__ W,
                     const float* __restrict__ a_s, const float* __restrict__ a_d,
                     unsigned short* __restrict__ Hb, float* __restrict__ sc_s,
                     float* __restrict__ sc_d, int nrows) {
    __shared__ float Wl[K * 64];
    __shared__ float Xl[64 * K];

    const int tid = threadIdx.x;
    const int tile0 = blockIdx.x * 64;

    for (int i = tid; i < K * 64 / 4; i += 256)
        reinterpret_cast<float4*>(Wl)[i] = reinterpret_cast<const float4*>(W)[i];
    for (int i = tid; i < 64 * K / 4; i += 256) {
        const int row = i / (K / 4);
        const int gr = tile0 + row;
        float4 v = make_float4(0.f, 0.f, 0.f, 0.f);
        if (gr < nrows) v = reinterpret_cast<const float4*>(X)[(size_t)gr * (K / 4) + (i % (K / 4))];
        reinterpret_cast<float4*>(Xl)[i] = v;
    }
    __syncthreads();

    const int lane = tid & 63;
    const int wave = tid >> 6;
    const float asl = a_s[lane];
    const float adl = a_d[lane];

#pragma unroll
    for (int g = 0; g < 4; g++) {
        const int r0 = wave * 16 + g * 4;
        if (tile0 + r0 >= nrows) break;
        float acc0 = 0.f, acc1 = 0.f, acc2 = 0.f, acc3 = 0.f;
        const float* xp0 = Xl + (size_t)(r0 + 0) * K;
        const float* xp1 = Xl + (size_t)(r0 + 1) * K;
        const float* xp2 = Xl + (size_t)(r0 + 2) * K;
        const float* xp3 = Xl + (size_t)(r0 + 3) * K;
#pragma unroll 2
        for (int k = 0; k < K; k += 4) {
            const float4 a = *reinterpret_cast<const float4*>(xp0 + k);
            const float4 b = *reinterpret_cast<const float4*>(xp1 + k);
            const float4 c = *reinterpret_cast<const float4*>(xp2 + k);
            const float4 d = *reinterpret_cast<const float4*>(xp3 + k);
            const float w0 = Wl[(k + 0) * 64 + lane];
            const float w1 = Wl[(k + 1) * 64 + lane];
            const float w2 = Wl[(k + 2) * 64 + lane];
            const float w3 = Wl[(k + 3) * 64 + lane];
            acc0 += a.x * w0 + a.y * w1 + a.z * w2 + a.w * w3;
            acc1 += b.x * w0 + b.y * w1 + b.z * w2 + b.w * w3;
            acc2 += c.x * w0 + c.y * w1 + c.z * w2 + c.w * w3;
            acc3 += d.x * w0 + d.y * w1 + d.z * w2 + d.w * w3;
        }
        const float accs[4] = {acc0, acc1, acc2, acc3};
#pragma unroll
        for (int r = 0; r < 4; r++) {
            const int gr = tile0 + r0 + r;
            if (gr >= nrows) break;
            Hb[(size_t)gr * 64 + lane] = f2bf(accs[r]);
            float ps = accs[r] * asl;
            float pd = accs[r] * adl;
#pragma unroll
            for (int off = 32; off; off >>= 1) {
                ps += __shfl_down(ps, off);
                pd += __shfl_down(pd, off);
            }
            if (lane == 0) {
                sc_s[gr] = ps;
                sc_d[gr] = pd;
            }
        }
    }
}

// ---------------- CSR build ----------------

__global__ void hist_kernel(const int* __restrict__ dst, int* __restrict__ cnt, int E) {
    const int tid = blockIdx.x * blockDim.x + threadIdx.x;
    const int stride = gridDim.x * blockDim.x;
    const int E4 = E >> 2;
    for (int i = tid; i < E4; i += stride) {
        int4 d = reinterpret_cast<const int4*>(dst)[i];
        atomicAdd(&cnt[d.x], 1);
        atomicAdd(&cnt[d.y], 1);
        atomicAdd(&cnt[d.z], 1);
        atomicAdd(&cnt[d.w], 1);
    }
    for (int i = (E4 << 2) + tid; i < E; i += stride) atomicAdd(&cnt[dst[i]], 1);
}

// ---- parallel 3-stage exclusive scan over cnt[0..N) -> rowptr[0..N] ----
#define SCAN_TILE 1024

__global__ void scan_partial_kernel(const int* __restrict__ cnt, int* __restrict__ partial, int N) {
    __shared__ int red[256];
    const int b = blockIdx.x;
    const int lo = b * SCAN_TILE;
    const int hi = min(lo + SCAN_TILE, N);
    int s = 0;
    for (int i = lo + threadIdx.x; i < hi; i += 256) s += cnt[i];
    red[threadIdx.x] = s;
    __syncthreads();
    for (int off = 128; off; off >>= 1) {
        if (threadIdx.x < off) red[threadIdx.x] += red[threadIdx.x + off];
        __syncthreads();
    }
    if (threadIdx.x == 0) partial[b] = red[0];
}

__global__ void scan_spine_kernel(int* __restrict__ partial, int nb) {
    __shared__ int s[1024];
    const int t = threadIdx.x;
    const int v = (t < nb) ? partial[t] : 0;
    s[t] = v;
    __syncthreads();
    for (int off = 1; off < 1024; off <<= 1) {
        int u = (t >= off) ? s[t - off] : 0;
        __syncthreads();
        s[t] += u;
        __syncthreads();
    }
    if (t < nb) partial[t] = s[t] - v;
}

__global__ void scan_emit_kernel(const int* __restrict__ cnt, const int* __restrict__ partial,
                                 int* __restrict__ rowptr, int N, int E) {
    __shared__ int red[256];
    const int b = blockIdx.x;
    const int t = threadIdx.x;
    const int base = b * SCAN_TILE + t * 4;
    int v[4];
    int s = 0;
#pragma unroll
    for (int k = 0; k < 4; k++) {
        const int i = base + k;
        v[k] = (i < N) ? cnt[i] : 0;
        s += v[k];
    }
    red[t] = s;
    __syncthreads();
    for (int off = 1; off < 256; off <<= 1) {
        int u = (t >= off) ? red[t - off] : 0;
        __syncthreads();
        red[t] += u;
        __syncthreads();
    }
    int excl = red[t] - s + partial[b];
#pragma unroll
    for (int k = 0; k < 4; k++) {
        const int i = base + k;
        if (i < N) rowptr[i] = excl;
        excl += v[k];
    }
    if (b == 0 && t == 0) rowptr[N] = E;
}

// XCD-private windowed scatter, single pass.
// - grid = 1024 blocks (4/CU, 16 waves/CU): ALL blocks co-resident at launch,
//   so the initial round-robin blockIdx%8 -> XCD assignment holds for the whole
//   kernel (no retirement churn). Window g is then written by ONE XCD only.
// - nontemporal loads for the streaming edge list: no L2 allocation, so the
//   dirty col/cursor window lines are not evicted early by the stream.
__global__ void scatter_kernel(const int* __restrict__ ei, const int* __restrict__ rowptr,
                               int* __restrict__ cursor, int* __restrict__ col,
                               int E, int N) {
    const int g = blockIdx.x & 7;
    const int win = (N + 7) / 8;
    const int lo = g * win;
    const int hi = min(lo + win, N);
    const int gtid = (blockIdx.x >> 3) * blockDim.x + threadIdx.x;
    const int gstride = (gridDim.x >> 3) * blockDim.x;
    for (int e = gtid; e < E; e += gstride) {
        const int d = __builtin_nontemporal_load(ei + E + e);
        if (d >= lo && d < hi) {
            const int pos = rowptr[d] + atomicAdd(&cursor[d], 1);
            col[pos] = __builtin_nontemporal_load(ei + e);
        }
    }
}

// ---------------- fused per-node online-softmax aggregation ----------------
template<bool RELU>
__global__ void gat_fused_agg(const int* __restrict__ rowptr, const int* __restrict__ col,
                              const float* __restrict__ sc_s, const float* __restrict__ sc_d,
                              const unsigned short* __restrict__ Hb, const float* __restrict__ bias,
                              float* __restrict__ Out, int N) {
    const int lane = threadIdx.x & 63;
    int gw = (blockIdx.x * blockDim.x + threadIdx.x) >> 6;
    const int nw = (gridDim.x * blockDim.x) >> 6;
    const float bl = bias[lane];
    for (int i = gw; i < N; i += nw) {
        const float scd = sc_d[i];
        float es = sc_s[i] + scd;
        es = es > 0.f ? es : 0.2f * es;   // self loop
        float m = es;
        float denom = 1.f;
        float acc = bf2f(Hb[(size_t)i * 64 + lane]);
        const int jb = rowptr[i], je = rowptr[i + 1];
        int j = jb;
        for (; j + 8 <= je; j += 8) {
            int s[8];
#pragma unroll
            for (int q = 0; q < 8; q++) s[q] = col[j + q];
            float e[8], h[8];
#pragma unroll
            for (int q = 0; q < 8; q++) {
                float ev = sc_s[s[q]] + scd;
                e[q] = ev > 0.f ? ev : 0.2f * ev;
                h[q] = bf2f(Hb[(size_t)s[q] * 64 + lane]);
            }
            float mn = m;
#pragma unroll
            for (int q = 0; q < 8; q++) mn = fmaxf(mn, e[q]);
            const float scale = __expf(m - mn);
            float w[8];
#pragma unroll
            for (int q = 0; q < 8; q++) w[q] = __expf(e[q] - mn);
            float dsum = 0.f, hsum = 0.f;
#pragma unroll
            for (int q = 0; q < 8; q++) {
                dsum += w[q];
                hsum += w[q] * h[q];
            }
            denom = denom * scale + dsum;
            acc = acc * scale + hsum;
            m = mn;
        }
        for (; j + 4 <= je; j += 4) {
            int s[4];
#pragma unroll
            for (int q = 0; q < 4; q++) s[q] = col[j + q];
            float e[4], h[4];
#pragma unroll
            for (int q = 0; q < 4; q++) {
                float ev = sc_s[s[q]] + scd;
                e[q] = ev > 0.f ? ev : 0.2f * ev;
                h[q] = bf2f(Hb[(size_t)s[q] * 64 + lane]);
            }
            float mn = fmaxf(fmaxf(fmaxf(e[0], e[1]), fmaxf(e[2], e[3])), m);
            const float scale = __expf(m - mn);
            float dsum = 0.f, hsum = 0.f;
#pragma unroll
            for (int q = 0; q < 4; q++) {
                float wq = __expf(e[q] - mn);
                dsum += wq;
                hsum += wq * h[q];
            }
            denom = denom * scale + dsum;
            acc = acc * scale + hsum;
            m = mn;
        }
        for (; j < je; j++) {
            const int s0 = col[j];
            float e0 = sc_s[s0] + scd;
            e0 = e0 > 0.f ? e0 : 0.2f * e0;
            const float h0 = bf2f(Hb[(size_t)s0 * 64 + lane]);
            const float mn = fmaxf(e0, m);
            const float scale = __expf(m - mn);
            const float w0 = __expf(e0 - mn);
            denom = denom * scale + w0;
            acc = acc * scale + w0 * h0;
            m = mn;
        }
        float o = acc / denom + bl;
        if (RELU) o = o > 0.f ? o : 0.f;
        Out[(size_t)i * 64 + lane] = o;
    }
}

// ---------------- pooling (batch is sorted: run-length accumulate) ----------------

__global__ void pool_kernel(const float* __restrict__ H, const int* __restrict__ batch,
                            float* __restrict__ sums, int* __restrict__ cnts, int N) {
    const int CHUNK = 256;
    const int lane = threadIdx.x & 63;
    int gw = (blockIdx.x * blockDim.x + threadIdx.x) >> 6;
    const int nw = (gridDim.x * blockDim.x) >> 6;
    const int nchunks = (N + CHUNK - 1) / CHUNK;
    for (int c = gw; c < nchunks; c += nw) {
        const int lo = c * CHUNK;
        const int hi = min(lo + CHUNK, N);
        int curb = batch[lo];
        float acc = 0.f;
        int cnt = 0;
        for (int n = lo; n < hi; n++) {
            int b = batch[n];
            if (b != curb) {
                unsafeAtomicAdd(&sums[(size_t)curb * 64 + lane], acc);
                if (lane == 0) atomicAdd(&cnts[curb], cnt);
                acc = 0.f; cnt = 0; curb = b;
            }
            acc += H[(size_t)n * 64 + lane];
            cnt++;
        }
        unsafeAtomicAdd(&sums[(size_t)curb * 64 + lane], acc);
        if (lane == 0) atomicAdd(&cnts[curb], cnt);
    }
}

// ---------------- final MLP + log_softmax ----------------
__global__ void mlp_kernel(const float* __restrict__ sums, const int* __restrict__ cnts,
                           const float* __restrict__ lw, const float* __restrict__ lb,
                           const float* __restrict__ cw, const float* __restrict__ cb,
                           float* __restrict__ out) {
    __shared__ float gv[64];
    __shared__ float z[32];
    __shared__ float logits[6];
    const int g = blockIdx.x;
    const int t = threadIdx.x;

    float cnt = (float)cnts[g];
    cnt = cnt > 1.f ? cnt : 1.f;
    gv[t] = sums[(size_t)g * 64 + t] / cnt;
    __syncthreads();

    if (t < 32) {
        float acc = lb[t];
#pragma unroll
        for (int k = 0; k < 64; k++) acc += gv[k] * lw[k * 32 + t];
        z[t] = acc > 0.f ? acc : 0.f;
    }
    __syncthreads();
    if (t < 6) {
        float acc = cb[t];
#pragma unroll
        for (int k = 0; k < 32; k++) acc += z[k] * cw[k * 6 + t];
        logits[t] = acc;
    }
    __syncthreads();
    if (t == 0) {
        float m = logits[0];
#pragma unroll
        for (int i = 1; i < 6; i++) m = fmaxf(m, logits[i]);
        float s = 0.f;
#pragma unroll
        for (int i = 0; i < 6; i++) s += expf(logits[i] - m);
        float lse = m + logf(s);
#pragma unroll
        for (int i = 0; i < 6; i++) out[(size_t)g * 6 + i] = logits[i] - lse;
    }
}

// ---------------- launch ----------------

extern "C" void kernel_launch(void* const* d_in, const int* in_sizes, int n_in,
                              void* d_out, int out_size, void* d_ws, size_t ws_size,
                              hipStream_t stream) {
    const float* x    = (const float*)d_in[0];
    const int*   ei   = (const int*)d_in[1];
    const int*   batch= (const int*)d_in[2];
    const float* W1   = (const float*)d_in[3];
    const float* as1  = (const float*)d_in[4];
    const float* ad1  = (const float*)d_in[5];
    const float* b1   = (const float*)d_in[6];
    const float* W2   = (const float*)d_in[7];
    const float* as2  = (const float*)d_in[8];
    const float* ad2  = (const float*)d_in[9];
    const float* b2   = (const float*)d_in[10];
    const float* lw   = (const float*)d_in[11];
    const float* lb   = (const float*)d_in[12];
    const float* cw   = (const float*)d_in[13];
    const float* cb   = (const float*)d_in[14];
    float* out = (float*)d_out;

    const int N  = in_sizes[0] / 128;
    const int E  = in_sizes[1] / 2;
    const int G  = out_size / 6;

    char* ws = (char*)d_ws;
    size_t off = 0;
    auto alloc = [&](size_t bytes) {
        void* p = ws + off;
        off += (bytes + 255) & ~size_t(255);
        return p;
    };
    float*          hB     = (float*)alloc((size_t)N * 64 * 4);
    unsigned short* Hb     = (unsigned short*)alloc((size_t)N * 64 * 2);
    float*          sc_s   = (float*)alloc((size_t)N * 4);
    float*          sc_d   = (float*)alloc((size_t)N * 4);
    int*            cnt    = (int*)alloc((size_t)N * 4);
    int*            cursor = (int*)alloc((size_t)N * 4);
    int*            rowptr = (int*)alloc((size_t)(N + 1) * 4);
    int*            colidx = (int*)alloc((size_t)E * 4);
    int*            partial= (int*)alloc((size_t)1024 * 4);
    float*          psum   = (float*)alloc((size_t)G * 64 * 4);
    int*            pcnt   = (int*)alloc((size_t)G * 4);
    (void)ws_size;

    const int TB = 256;
    const int gemm_grid = (N + 63) / 64;
    const int scan_blocks = (N + SCAN_TILE - 1) / SCAN_TILE;

    // ---- CSR build by dst ----
    hipMemsetAsync(cnt, 0, (size_t)N * 4, stream);
    hipMemsetAsync(cursor, 0, (size_t)N * 4, stream);
    hist_kernel<<<2048, TB, 0, stream>>>(ei + E, cnt, E);
    scan_partial_kernel<<<scan_blocks, 256, 0, stream>>>(cnt, partial, N);
    scan_spine_kernel<<<1, 1024, 0, stream>>>(partial, scan_blocks);
    scan_emit_kernel<<<scan_blocks, 256, 0, stream>>>(cnt, partial, rowptr, N, E);
    scatter_kernel<<<1024, TB, 0, stream>>>(ei, rowptr, cursor, colidx, E, N);

    // ---- layer 1 ----
    gat_gemm_kernel<128><<<gemm_grid, TB, 0, stream>>>(x, W1, as1, ad1, Hb, sc_s, sc_d, N);
    gat_fused_agg<true><<<2048, TB, 0, stream>>>(rowptr, colidx, sc_s, sc_d, Hb, b1, hB, N);

    // ---- layer 2 ----
    gat_gemm_kernel<64><<<gemm_grid, TB, 0, stream>>>(hB, W2, as2, ad2, Hb, sc_s, sc_d, N);
    gat_fused_agg<false><<<2048, TB, 0, stream>>>(rowptr, colidx, sc_s, sc_d, Hb, b2, hB, N);

    // ---- pooling + MLP head ----
    hipMemsetAsync(psum, 0, (size_t)G * 64 * 4, stream);
    hipMemsetAsync(pcnt, 0, (size_t)G * 4, stream);
    pool_kernel<<<128, TB, 0, stream>>>(hB, batch, psum, pcnt, N);
    mlp_kernel<<<G, 64, 0, stream>>>(psum, pcnt, lw, lb, cw, cb, out);
}

// Round 9
// 632.392 us; speedup vs baseline: 1.2246x; 1.2246x over previous
//
#include <hip/hip_runtime.h>

// ---------------- bf16 helpers ----------------

__device__ __forceinline__ unsigned short f2bf(float f) {
    unsigned u = __float_as_uint(f);
    unsigned r = (u + 0x7FFFu + ((u >> 16) & 1u)) >> 16;
    return (unsigned short)r;
}
__device__ __forceinline__ float bf2f(unsigned short u) {
    return __uint_as_float(((unsigned)u) << 16);
}

// ---------------- node GEMM + attention scores ----------------
template<int K>
__global__ __launch_bounds__(256, 2)
void gat_gemm_kernel(const float* __restrict__ X, const float* __restrict__ W,
                     const float* __restrict__ a_s, const float* __restrict__ a_d,
                     unsigned short* __restrict__ Hb, float* __restrict__ sc_s,
                     float* __restrict__ sc_d, int nrows) {
    __shared__ float Wl[K * 64];
    __shared__ float Xl[64 * K];

    const int tid = threadIdx.x;
    const int tile0 = blockIdx.x * 64;

    for (int i = tid; i < K * 64 / 4; i += 256)
        reinterpret_cast<float4*>(Wl)[i] = reinterpret_cast<const float4*>(W)[i];
    for (int i = tid; i < 64 * K / 4; i += 256) {
        const int row = i / (K / 4);
        const int gr = tile0 + row;
        float4 v = make_float4(0.f, 0.f, 0.f, 0.f);
        if (gr < nrows) v = reinterpret_cast<const float4*>(X)[(size_t)gr * (K / 4) + (i % (K / 4))];
        reinterpret_cast<float4*>(Xl)[i] = v;
    }
    __syncthreads();

    const int lane = tid & 63;
    const int wave = tid >> 6;
    const float asl = a_s[lane];
    const float adl = a_d[lane];

#pragma unroll
    for (int g = 0; g < 4; g++) {
        const int r0 = wave * 16 + g * 4;
        if (tile0 + r0 >= nrows) break;
        float acc0 = 0.f, acc1 = 0.f, acc2 = 0.f, acc3 = 0.f;
        const float* xp0 = Xl + (size_t)(r0 + 0) * K;
        const float* xp1 = Xl + (size_t)(r0 + 1) * K;
        const float* xp2 = Xl + (size_t)(r0 + 2) * K;
        const float* xp3 = Xl + (size_t)(r0 + 3) * K;
#pragma unroll 2
        for (int k = 0; k < K; k += 4) {
            const float4 a = *reinterpret_cast<const float4*>(xp0 + k);
            const float4 b = *reinterpret_cast<const float4*>(xp1 + k);
            const float4 c = *reinterpret_cast<const float4*>(xp2 + k);
            const float4 d = *reinterpret_cast<const float4*>(xp3 + k);
            const float w0 = Wl[(k + 0) * 64 + lane];
            const float w1 = Wl[(k + 1) * 64 + lane];
            const float w2 = Wl[(k + 2) * 64 + lane];
            const float w3 = Wl[(k + 3) * 64 + lane];
            acc0 += a.x * w0 + a.y * w1 + a.z * w2 + a.w * w3;
            acc1 += b.x * w0 + b.y * w1 + b.z * w2 + b.w * w3;
            acc2 += c.x * w0 + c.y * w1 + c.z * w2 + c.w * w3;
            acc3 += d.x * w0 + d.y * w1 + d.z * w2 + d.w * w3;
        }
        const float accs[4] = {acc0, acc1, acc2, acc3};
#pragma unroll
        for (int r = 0; r < 4; r++) {
            const int gr = tile0 + r0 + r;
            if (gr >= nrows) break;
            Hb[(size_t)gr * 64 + lane] = f2bf(accs[r]);
            float ps = accs[r] * asl;
            float pd = accs[r] * adl;
#pragma unroll
            for (int off = 32; off; off >>= 1) {
                ps += __shfl_down(ps, off);
                pd += __shfl_down(pd, off);
            }
            if (lane == 0) {
                sc_s[gr] = ps;
                sc_d[gr] = pd;
            }
        }
    }
}

// ---------------- CSR build ----------------

__global__ void hist_kernel(const int* __restrict__ dst, int* __restrict__ cnt, int E) {
    const int tid = blockIdx.x * blockDim.x + threadIdx.x;
    const int stride = gridDim.x * blockDim.x;
    const int E4 = E >> 2;
    for (int i = tid; i < E4; i += stride) {
        int4 d = reinterpret_cast<const int4*>(dst)[i];
        atomicAdd(&cnt[d.x], 1);
        atomicAdd(&cnt[d.y], 1);
        atomicAdd(&cnt[d.z], 1);
        atomicAdd(&cnt[d.w], 1);
    }
    for (int i = (E4 << 2) + tid; i < E; i += stride) atomicAdd(&cnt[dst[i]], 1);
}

#define SCAN_TILE 1024

__global__ void scan_partial_kernel(const int* __restrict__ cnt, int* __restrict__ partial, int N) {
    __shared__ int red[256];
    const int b = blockIdx.x;
    const int lo = b * SCAN_TILE;
    const int hi = min(lo + SCAN_TILE, N);
    int s = 0;
    for (int i = lo + threadIdx.x; i < hi; i += 256) s += cnt[i];
    red[threadIdx.x] = s;
    __syncthreads();
    for (int off = 128; off; off >>= 1) {
        if (threadIdx.x < off) red[threadIdx.x] += red[threadIdx.x + off];
        __syncthreads();
    }
    if (threadIdx.x == 0) partial[b] = red[0];
}

__global__ void scan_spine_kernel(int* __restrict__ partial, int nb) {
    __shared__ int s[1024];
    const int t = threadIdx.x;
    const int v = (t < nb) ? partial[t] : 0;
    s[t] = v;
    __syncthreads();
    for (int off = 1; off < 1024; off <<= 1) {
        int u = (t >= off) ? s[t - off] : 0;
        __syncthreads();
        s[t] += u;
        __syncthreads();
    }
    if (t < nb) partial[t] = s[t] - v;
}

__global__ void scan_emit_kernel(const int* __restrict__ cnt, const int* __restrict__ partial,
                                 int* __restrict__ rowptr, int N, int E) {
    __shared__ int red[256];
    const int b = blockIdx.x;
    const int t = threadIdx.x;
    const int base = b * SCAN_TILE + t * 4;
    int v[4];
    int s = 0;
#pragma unroll
    for (int k = 0; k < 4; k++) {
        const int i = base + k;
        v[k] = (i < N) ? cnt[i] : 0;
        s += v[k];
    }
    red[t] = s;
    __syncthreads();
    for (int off = 1; off < 256; off <<= 1) {
        int u = (t >= off) ? red[t - off] : 0;
        __syncthreads();
        red[t] += u;
        __syncthreads();
    }
    int excl = red[t] - s + partial[b];
#pragma unroll
    for (int k = 0; k < 4; k++) {
        const int i = base + k;
        if (i < N) rowptr[i] = excl;
        excl += v[k];
    }
    if (b == 0 && t == 0) rowptr[N] = E;
}

// ---------------- two-phase bucketed edge sort (replaces random scatter) ----
// Bucket = 512 consecutive dst nodes. Bucket b's final col range is exactly
// [rowptr[512b], rowptr[512(b+1)]) so staged[] shares col's indexing.
#define BSZ   512
#define NBITS 9
#define CH    4096     // edges per partition block

__global__ void bucket_init_kernel(const int* __restrict__ rowptr, int* __restrict__ bcur,
                                   int NB) {
    const int t = blockIdx.x * blockDim.x + threadIdx.x;
    if (t < NB) bcur[t] = rowptr[t * BSZ];
}

// Phase C: per-block LDS counting sort into bucket runs; ONE global atomic per
// (block,bucket) reserves space; runs written contiguously (coalesced).
// pack = (dst & 511) << 17 | src   (requires N <= 131072)
__global__ __launch_bounds__(256)
void partition_kernel(const int* __restrict__ ei, int E,
                      int* __restrict__ bcur, unsigned* __restrict__ staged) {
    __shared__ int cnt[256], scantmp[256], excl[256], cnt2[256], gbase[256];
    __shared__ unsigned packed[CH];
    __shared__ unsigned char bid[CH];
    const int t = threadIdx.x;
    const int e0 = blockIdx.x * CH;

    cnt[t] = 0;
    cnt2[t] = 0;
    __syncthreads();

    unsigned pk[16];
    int bb[16];
#pragma unroll
    for (int i = 0; i < 16; i++) {
        const int e = e0 + i * 256 + t;
        if (e < E) {
            const int d = ei[E + e];
            const int s = ei[e];
            bb[i] = d >> NBITS;
            pk[i] = ((unsigned)(d & (BSZ - 1)) << 17) | (unsigned)s;
            atomicAdd(&cnt[bb[i]], 1);
        } else bb[i] = -1;
    }
    __syncthreads();

    // exclusive scan of cnt[0..255] -> excl
    int v = cnt[t];
    scantmp[t] = v;
    __syncthreads();
    for (int off = 1; off < 256; off <<= 1) {
        int u = (t >= off) ? scantmp[t - off] : 0;
        __syncthreads();
        scantmp[t] += u;
        __syncthreads();
    }
    excl[t] = scantmp[t] - v;
    if (v > 0) gbase[t] = atomicAdd(&bcur[t], v);
    __syncthreads();

#pragma unroll
    for (int i = 0; i < 16; i++) {
        if (bb[i] >= 0) {
            const int slot = atomicAdd(&cnt2[bb[i]], 1);
            const int p = excl[bb[i]] + slot;
            packed[p] = pk[i];
            bid[p] = (unsigned char)bb[i];
        }
    }
    __syncthreads();

    const int nvalid = min(CH, E - e0);
    for (int i = t; i < nvalid; i += 256) {
        const int b = bid[i];
        staged[gbase[b] + (i - excl[b])] = packed[i];
    }
}

// Phase D: one block per bucket; exact per-node placement with LDS cursors.
// col writes land in a ~65KB single-block-owned (single-XCD) region.
__global__ __launch_bounds__(256)
void place_kernel(const unsigned* __restrict__ staged, const int* __restrict__ rowptr,
                  int* __restrict__ col, int N) {
    __shared__ int rp[BSZ];
    __shared__ int nc[BSZ];
    const int b = blockIdx.x;
    const int n0 = b * BSZ;
    const int nn = min(BSZ, N - n0);
    for (int i = threadIdx.x; i < nn; i += 256) {
        rp[i] = rowptr[n0 + i];
        nc[i] = 0;
    }
    __syncthreads();
    const int lo = rowptr[n0];
    const int hi = rowptr[n0 + nn];
    for (int e = lo + threadIdx.x; e < hi; e += 256) {
        const unsigned p = staged[e];
        const int dlo = (int)(p >> 17);
        const int src = (int)(p & 0x1FFFFu);
        const int pos = rp[dlo] + atomicAdd(&nc[dlo], 1);
        col[pos] = src;
    }
}

// ---------------- fused per-node online-softmax aggregation ----------------
template<bool RELU>
__global__ void gat_fused_agg(const int* __restrict__ rowptr, const int* __restrict__ col,
                              const float* __restrict__ sc_s, const float* __restrict__ sc_d,
                              const unsigned short* __restrict__ Hb, const float* __restrict__ bias,
                              float* __restrict__ Out, int N) {
    const int lane = threadIdx.x & 63;
    int gw = (blockIdx.x * blockDim.x + threadIdx.x) >> 6;
    const int nw = (gridDim.x * blockDim.x) >> 6;
    const float bl = bias[lane];
    for (int i = gw; i < N; i += nw) {
        const float scd = sc_d[i];
        float es = sc_s[i] + scd;
        es = es > 0.f ? es : 0.2f * es;   // self loop
        float m = es;
        float denom = 1.f;
        float acc = bf2f(Hb[(size_t)i * 64 + lane]);
        const int jb = rowptr[i], je = rowptr[i + 1];
        int j = jb;
        for (; j + 8 <= je; j += 8) {
            int s[8];
#pragma unroll
            for (int q = 0; q < 8; q++) s[q] = col[j + q];
            float e[8], h[8];
#pragma unroll
            for (int q = 0; q < 8; q++) {
                float ev = sc_s[s[q]] + scd;
                e[q] = ev > 0.f ? ev : 0.2f * ev;
                h[q] = bf2f(Hb[(size_t)s[q] * 64 + lane]);
            }
            float mn = m;
#pragma unroll
            for (int q = 0; q < 8; q++) mn = fmaxf(mn, e[q]);
            const float scale = __expf(m - mn);
            float w[8];
#pragma unroll
            for (int q = 0; q < 8; q++) w[q] = __expf(e[q] - mn);
            float dsum = 0.f, hsum = 0.f;
#pragma unroll
            for (int q = 0; q < 8; q++) {
                dsum += w[q];
                hsum += w[q] * h[q];
            }
            denom = denom * scale + dsum;
            acc = acc * scale + hsum;
            m = mn;
        }
        for (; j + 4 <= je; j += 4) {
            int s[4];
#pragma unroll
            for (int q = 0; q < 4; q++) s[q] = col[j + q];
            float e[4], h[4];
#pragma unroll
            for (int q = 0; q < 4; q++) {
                float ev = sc_s[s[q]] + scd;
                e[q] = ev > 0.f ? ev : 0.2f * ev;
                h[q] = bf2f(Hb[(size_t)s[q] * 64 + lane]);
            }
            float mn = fmaxf(fmaxf(fmaxf(e[0], e[1]), fmaxf(e[2], e[3])), m);
            const float scale = __expf(m - mn);
            float dsum = 0.f, hsum = 0.f;
#pragma unroll
            for (int q = 0; q < 4; q++) {
                float wq = __expf(e[q] - mn);
                dsum += wq;
                hsum += wq * h[q];
            }
            denom = denom * scale + dsum;
            acc = acc * scale + hsum;
            m = mn;
        }
        for (; j < je; j++) {
            const int s0 = col[j];
            float e0 = sc_s[s0] + scd;
            e0 = e0 > 0.f ? e0 : 0.2f * e0;
            const float h0 = bf2f(Hb[(size_t)s0 * 64 + lane]);
            const float mn = fmaxf(e0, m);
            const float scale = __expf(m - mn);
            const float w0 = __expf(e0 - mn);
            denom = denom * scale + w0;
            acc = acc * scale + w0 * h0;
            m = mn;
        }
        float o = acc / denom + bl;
        if (RELU) o = o > 0.f ? o : 0.f;
        Out[(size_t)i * 64 + lane] = o;
    }
}

// ---------------- pooling (batch is sorted: run-length accumulate) ----------------

__global__ void pool_kernel(const float* __restrict__ H, const int* __restrict__ batch,
                            float* __restrict__ sums, int* __restrict__ cnts, int N) {
    const int CHUNK = 256;
    const int lane = threadIdx.x & 63;
    int gw = (blockIdx.x * blockDim.x + threadIdx.x) >> 6;
    const int nw = (gridDim.x * blockDim.x) >> 6;
    const int nchunks = (N + CHUNK - 1) / CHUNK;
    for (int c = gw; c < nchunks; c += nw) {
        const int lo = c * CHUNK;
        const int hi = min(lo + CHUNK, N);
        int curb = batch[lo];
        float acc = 0.f;
        int cnt = 0;
        for (int n = lo; n < hi; n++) {
            int b = batch[n];
            if (b != curb) {
                unsafeAtomicAdd(&sums[(size_t)curb * 64 + lane], acc);
                if (lane == 0) atomicAdd(&cnts[curb], cnt);
                acc = 0.f; cnt = 0; curb = b;
            }
            acc += H[(size_t)n * 64 + lane];
            cnt++;
        }
        unsafeAtomicAdd(&sums[(size_t)curb * 64 + lane], acc);
        if (lane == 0) atomicAdd(&cnts[curb], cnt);
    }
}

// ---------------- final MLP + log_softmax ----------------
__global__ void mlp_kernel(const float* __restrict__ sums, const int* __restrict__ cnts,
                           const float* __restrict__ lw, const float* __restrict__ lb,
                           const float* __restrict__ cw, const float* __restrict__ cb,
                           float* __restrict__ out) {
    __shared__ float gv[64];
    __shared__ float z[32];
    __shared__ float logits[6];
    const int g = blockIdx.x;
    const int t = threadIdx.x;

    float cnt = (float)cnts[g];
    cnt = cnt > 1.f ? cnt : 1.f;
    gv[t] = sums[(size_t)g * 64 + t] / cnt;
    __syncthreads();

    if (t < 32) {
        float acc = lb[t];
#pragma unroll
        for (int k = 0; k < 64; k++) acc += gv[k] * lw[k * 32 + t];
        z[t] = acc > 0.f ? acc : 0.f;
    }
    __syncthreads();
    if (t < 6) {
        float acc = cb[t];
#pragma unroll
        for (int k = 0; k < 32; k++) acc += z[k] * cw[k * 6 + t];
        logits[t] = acc;
    }
    __syncthreads();
    if (t == 0) {
        float m = logits[0];
#pragma unroll
        for (int i = 1; i < 6; i++) m = fmaxf(m, logits[i]);
        float s = 0.f;
#pragma unroll
        for (int i = 0; i < 6; i++) s += expf(logits[i] - m);
        float lse = m + logf(s);
#pragma unroll
        for (int i = 0; i < 6; i++) out[(size_t)g * 6 + i] = logits[i] - lse;
    }
}

// ---------------- launch ----------------

extern "C" void kernel_launch(void* const* d_in, const int* in_sizes, int n_in,
                              void* d_out, int out_size, void* d_ws, size_t ws_size,
                              hipStream_t stream) {
    const float* x    = (const float*)d_in[0];
    const int*   ei   = (const int*)d_in[1];
    const int*   batch= (const int*)d_in[2];
    const float* W1   = (const float*)d_in[3];
    const float* as1  = (const float*)d_in[4];
    const float* ad1  = (const float*)d_in[5];
    const float* b1   = (const float*)d_in[6];
    const float* W2   = (const float*)d_in[7];
    const float* as2  = (const float*)d_in[8];
    const float* ad2  = (const float*)d_in[9];
    const float* b2   = (const float*)d_in[10];
    const float* lw   = (const float*)d_in[11];
    const float* lb   = (const float*)d_in[12];
    const float* cw   = (const float*)d_in[13];
    const float* cb   = (const float*)d_in[14];
    float* out = (float*)d_out;

    const int N  = in_sizes[0] / 128;
    const int E  = in_sizes[1] / 2;
    const int G  = out_size / 6;
    const int NB = (N + BSZ - 1) / BSZ;

    char* ws = (char*)d_ws;
    size_t off = 0;
    auto alloc = [&](size_t bytes) {
        void* p = ws + off;
        off += (bytes + 255) & ~size_t(255);
        return p;
    };
    float*          hB     = (float*)alloc((size_t)N * 64 * 4);
    unsigned short* Hb     = (unsigned short*)alloc((size_t)N * 64 * 2);
    float*          sc_s   = (float*)alloc((size_t)N * 4);
    float*          sc_d   = (float*)alloc((size_t)N * 4);
    int*            cnt    = (int*)alloc((size_t)N * 4);
    int*            rowptr = (int*)alloc((size_t)(N + 1) * 4);
    int*            colidx = (int*)alloc((size_t)E * 4);
    unsigned*       staged = (unsigned*)alloc((size_t)E * 4);
    int*            bcur   = (int*)alloc((size_t)NB * 4);
    int*            partial= (int*)alloc((size_t)1024 * 4);
    float*          psum   = (float*)alloc((size_t)G * 64 * 4);
    int*            pcnt   = (int*)alloc((size_t)G * 4);
    (void)ws_size;

    const int TB = 256;
    const int gemm_grid = (N + 63) / 64;
    const int scan_blocks = (N + SCAN_TILE - 1) / SCAN_TILE;
    const int part_blocks = (E + CH - 1) / CH;

    // ---- CSR build by dst (hist -> scan -> bucket partition -> place) ----
    hipMemsetAsync(cnt, 0, (size_t)N * 4, stream);
    hist_kernel<<<2048, TB, 0, stream>>>(ei + E, cnt, E);
    scan_partial_kernel<<<scan_blocks, 256, 0, stream>>>(cnt, partial, N);
    scan_spine_kernel<<<1, 1024, 0, stream>>>(partial, scan_blocks);
    scan_emit_kernel<<<scan_blocks, 256, 0, stream>>>(cnt, partial, rowptr, N, E);
    bucket_init_kernel<<<(NB + 255) / 256, 256, 0, stream>>>(rowptr, bcur, NB);
    partition_kernel<<<part_blocks, 256, 0, stream>>>(ei, E, bcur, staged);
    place_kernel<<<NB, 256, 0, stream>>>(staged, rowptr, colidx, N);

    // ---- layer 1 ----
    gat_gemm_kernel<128><<<gemm_grid, TB, 0, stream>>>(x, W1, as1, ad1, Hb, sc_s, sc_d, N);
    gat_fused_agg<true><<<2048, TB, 0, stream>>>(rowptr, colidx, sc_s, sc_d, Hb, b1, hB, N);

    // ---- layer 2 ----
    gat_gemm_kernel<64><<<gemm_grid, TB, 0, stream>>>(hB, W2, as2, ad2, Hb, sc_s, sc_d, N);
    gat_fused_agg<false><<<2048, TB, 0, stream>>>(rowptr, colidx, sc_s, sc_d, Hb, b2, hB, N);

    // ---- pooling + MLP head ----
    hipMemsetAsync(psum, 0, (size_t)G * 64 * 4, stream);
    hipMemsetAsync(pcnt, 0, (size_t)G * 4, stream);
    pool_kernel<<<128, TB, 0, stream>>>(hB, batch, psum, pcnt, N);
    mlp_kernel<<<G, 64, 0, stream>>>(psum, pcnt, lw, lb, cw, cb, out);
}

// Round 10
// 533.051 us; speedup vs baseline: 1.4528x; 1.1864x over previous
//
#include <hip/hip_runtime.h>

// ---------------- bf16 helpers ----------------

__device__ __forceinline__ unsigned short f2bf(float f) {
    unsigned u = __float_as_uint(f);
    unsigned r = (u + 0x7FFFu + ((u >> 16) & 1u)) >> 16;
    return (unsigned short)r;
}
__device__ __forceinline__ float bf2f(unsigned short u) {
    return __uint_as_float(((unsigned)u) << 16);
}

// ---------------- node GEMM + attention scores ----------------
template<int K>
__global__ __launch_bounds__(256, 2)
void gat_gemm_kernel(const float* __restrict__ X, const float* __restrict__ W,
                     const float* __restrict__ a_s, const float* __restrict__ a_d,
                     unsigned short* __restrict__ Hb, float* __restrict__ sc_s,
                     float* __restrict__ sc_d, int nrows) {
    __shared__ float Wl[K * 64];
    __shared__ float Xl[64 * K];

    const int tid = threadIdx.x;
    const int tile0 = blockIdx.x * 64;

    for (int i = tid; i < K * 64 / 4; i += 256)
        reinterpret_cast<float4*>(Wl)[i] = reinterpret_cast<const float4*>(W)[i];
    for (int i = tid; i < 64 * K / 4; i += 256) {
        const int row = i / (K / 4);
        const int gr = tile0 + row;
        float4 v = make_float4(0.f, 0.f, 0.f, 0.f);
        if (gr < nrows) v = reinterpret_cast<const float4*>(X)[(size_t)gr * (K / 4) + (i % (K / 4))];
        reinterpret_cast<float4*>(Xl)[i] = v;
    }
    __syncthreads();

    const int lane = tid & 63;
    const int wave = tid >> 6;
    const float asl = a_s[lane];
    const float adl = a_d[lane];

#pragma unroll
    for (int g = 0; g < 4; g++) {
        const int r0 = wave * 16 + g * 4;
        if (tile0 + r0 >= nrows) break;
        float acc0 = 0.f, acc1 = 0.f, acc2 = 0.f, acc3 = 0.f;
        const float* xp0 = Xl + (size_t)(r0 + 0) * K;
        const float* xp1 = Xl + (size_t)(r0 + 1) * K;
        const float* xp2 = Xl + (size_t)(r0 + 2) * K;
        const float* xp3 = Xl + (size_t)(r0 + 3) * K;
#pragma unroll 2
        for (int k = 0; k < K; k += 4) {
            const float4 a = *reinterpret_cast<const float4*>(xp0 + k);
            const float4 b = *reinterpret_cast<const float4*>(xp1 + k);
            const float4 c = *reinterpret_cast<const float4*>(xp2 + k);
            const float4 d = *reinterpret_cast<const float4*>(xp3 + k);
            const float w0 = Wl[(k + 0) * 64 + lane];
            const float w1 = Wl[(k + 1) * 64 + lane];
            const float w2 = Wl[(k + 2) * 64 + lane];
            const float w3 = Wl[(k + 3) * 64 + lane];
            acc0 += a.x * w0 + a.y * w1 + a.z * w2 + a.w * w3;
            acc1 += b.x * w0 + b.y * w1 + b.z * w2 + b.w * w3;
            acc2 += c.x * w0 + c.y * w1 + c.z * w2 + c.w * w3;
            acc3 += d.x * w0 + d.y * w1 + d.z * w2 + d.w * w3;
        }
        const float accs[4] = {acc0, acc1, acc2, acc3};
#pragma unroll
        for (int r = 0; r < 4; r++) {
            const int gr = tile0 + r0 + r;
            if (gr >= nrows) break;
            Hb[(size_t)gr * 64 + lane] = f2bf(accs[r]);
            float ps = accs[r] * asl;
            float pd = accs[r] * adl;
#pragma unroll
            for (int off = 32; off; off >>= 1) {
                ps += __shfl_down(ps, off);
                pd += __shfl_down(pd, off);
            }
            if (lane == 0) {
                sc_s[gr] = ps;
                sc_d[gr] = pd;
            }
        }
    }
}

// ---------------- CSR build: bucket hist -> bucket scan -> partition -> place
// Bucket = 512 consecutive dst nodes (NB <= 256). No per-node global histogram:
// per-node offsets are derived in LDS inside place_kernel, which also emits
// rowptr coalesced. No per-edge global atomics anywhere.
#define BSZ   512
#define NBITS 9
#define CH    4096     // edges per partition block

// per-block LDS histogram over buckets, one global flush per (block,bucket)
__global__ __launch_bounds__(256)
void bucket_hist_kernel(const int* __restrict__ dst, int* __restrict__ bhist, int E) {
    __shared__ int cnt[256];
    const int t = threadIdx.x;
    cnt[t] = 0;
    __syncthreads();
    const int tid = blockIdx.x * blockDim.x + t;
    const int stride = gridDim.x * blockDim.x;
    const int E4 = E >> 2;
    for (int i = tid; i < E4; i += stride) {
        const int4 d = reinterpret_cast<const int4*>(dst)[i];
        atomicAdd(&cnt[d.x >> NBITS], 1);
        atomicAdd(&cnt[d.y >> NBITS], 1);
        atomicAdd(&cnt[d.z >> NBITS], 1);
        atomicAdd(&cnt[d.w >> NBITS], 1);
    }
    for (int i = (E4 << 2) + tid; i < E; i += stride)
        atomicAdd(&cnt[dst[i] >> NBITS], 1);
    __syncthreads();
    if (cnt[t] > 0) atomicAdd(&bhist[t], cnt[t]);
}

// exclusive scan of bhist[0..NB) -> bbase (and working copy bcur); bbase[NB]=E
__global__ void bucket_scan_kernel(const int* __restrict__ bhist, int* __restrict__ bbase,
                                   int* __restrict__ bcur, int NB, int E) {
    __shared__ int s[256];
    const int t = threadIdx.x;
    const int v = (t < NB) ? bhist[t] : 0;
    s[t] = v;
    __syncthreads();
    for (int off = 1; off < 256; off <<= 1) {
        int u = (t >= off) ? s[t - off] : 0;
        __syncthreads();
        s[t] += u;
        __syncthreads();
    }
    if (t < NB) {
        const int excl = s[t] - v;
        bbase[t] = excl;
        bcur[t] = excl;
    }
    if (t == 0) bbase[NB] = E;
}

// Phase C: per-block LDS counting sort into bucket runs; ONE global atomic per
// (block,bucket) reserves space; runs written contiguously (coalesced).
// pack = (dst & 511) << 17 | src   (requires N <= 131072)
__global__ __launch_bounds__(256)
void partition_kernel(const int* __restrict__ ei, int E,
                      int* __restrict__ bcur, unsigned* __restrict__ staged) {
    __shared__ int cnt[256], scantmp[256], excl[256], cnt2[256], gbase[256];
    __shared__ unsigned packed[CH];
    __shared__ unsigned char bid[CH];
    const int t = threadIdx.x;
    const int e0 = blockIdx.x * CH;

    cnt[t] = 0;
    cnt2[t] = 0;
    __syncthreads();

    unsigned pk[16];
    int bb[16];
#pragma unroll
    for (int i = 0; i < 16; i++) {
        const int e = e0 + i * 256 + t;
        if (e < E) {
            const int d = ei[E + e];
            const int s = ei[e];
            bb[i] = d >> NBITS;
            pk[i] = ((unsigned)(d & (BSZ - 1)) << 17) | (unsigned)s;
            atomicAdd(&cnt[bb[i]], 1);
        } else bb[i] = -1;
    }
    __syncthreads();

    int v = cnt[t];
    scantmp[t] = v;
    __syncthreads();
    for (int off = 1; off < 256; off <<= 1) {
        int u = (t >= off) ? scantmp[t - off] : 0;
        __syncthreads();
        scantmp[t] += u;
        __syncthreads();
    }
    excl[t] = scantmp[t] - v;
    if (v > 0) gbase[t] = atomicAdd(&bcur[t], v);
    __syncthreads();

#pragma unroll
    for (int i = 0; i < 16; i++) {
        if (bb[i] >= 0) {
            const int slot = atomicAdd(&cnt2[bb[i]], 1);
            const int p = excl[bb[i]] + slot;
            packed[p] = pk[i];
            bid[p] = (unsigned char)bb[i];
        }
    }
    __syncthreads();

    const int nvalid = min(CH, E - e0);
    for (int i = t; i < nvalid; i += 256) {
        const int b = bid[i];
        staged[gbase[b] + (i - excl[b])] = packed[i];
    }
}

// Phase D: one block per bucket. LDS per-node count -> LDS scan -> emit rowptr
// (coalesced) -> exact placement. col writes land in a ~65KB block-owned region.
__global__ __launch_bounds__(256)
void place_kernel(const unsigned* __restrict__ staged, const int* __restrict__ bbase,
                  int* __restrict__ rowptr, int* __restrict__ col, int N, int E, int NB) {
    __shared__ int nc[BSZ];
    __shared__ int rp[BSZ];
    __shared__ int pairs[256];
    const int b = blockIdx.x;
    const int n0 = b * BSZ;
    const int nn = min(BSZ, N - n0);
    const int t = threadIdx.x;

    nc[t] = 0;
    nc[t + 256] = 0;
    __syncthreads();

    const int lo = bbase[b];
    const int hi = bbase[b + 1];
    for (int e = lo + t; e < hi; e += 256)
        atomicAdd(&nc[staged[e] >> 17], 1);
    __syncthreads();

    // exclusive scan over nc[0..511] via 256 pair-sums
    const int c0 = nc[2 * t], c1 = nc[2 * t + 1];
    const int ps = c0 + c1;
    pairs[t] = ps;
    __syncthreads();
    for (int off = 1; off < 256; off <<= 1) {
        int u = (t >= off) ? pairs[t - off] : 0;
        __syncthreads();
        pairs[t] += u;
        __syncthreads();
    }
    const int pexcl = pairs[t] - ps;
    rp[2 * t]     = lo + pexcl;
    rp[2 * t + 1] = lo + pexcl + c0;
    nc[2 * t] = 0;
    nc[2 * t + 1] = 0;
    __syncthreads();

    // emit rowptr (coalesced)
    for (int i = t; i < nn; i += 256) rowptr[n0 + i] = rp[i];
    if (b == NB - 1 && t == 0) rowptr[N] = E;

    // place edges
    for (int e = lo + t; e < hi; e += 256) {
        const unsigned p = staged[e];
        const int dlo = (int)(p >> 17);
        const int src = (int)(p & 0x1FFFFu);
        const int pos = rp[dlo] + atomicAdd(&nc[dlo], 1);
        col[pos] = src;
    }
}

// ---------------- fused per-node online-softmax aggregation ----------------
template<bool RELU>
__global__ void gat_fused_agg(const int* __restrict__ rowptr, const int* __restrict__ col,
                              const float* __restrict__ sc_s, const float* __restrict__ sc_d,
                              const unsigned short* __restrict__ Hb, const float* __restrict__ bias,
                              float* __restrict__ Out, int N) {
    const int lane = threadIdx.x & 63;
    int gw = (blockIdx.x * blockDim.x + threadIdx.x) >> 6;
    const int nw = (gridDim.x * blockDim.x) >> 6;
    const float bl = bias[lane];
    for (int i = gw; i < N; i += nw) {
        const float scd = sc_d[i];
        float es = sc_s[i] + scd;
        es = es > 0.f ? es : 0.2f * es;   // self loop
        float m = es;
        float denom = 1.f;
        float acc = bf2f(Hb[(size_t)i * 64 + lane]);
        const int jb = rowptr[i], je = rowptr[i + 1];
        int j = jb;
        for (; j + 8 <= je; j += 8) {
            int s[8];
#pragma unroll
            for (int q = 0; q < 8; q++) s[q] = col[j + q];
            float e[8], h[8];
#pragma unroll
            for (int q = 0; q < 8; q++) {
                float ev = sc_s[s[q]] + scd;
                e[q] = ev > 0.f ? ev : 0.2f * ev;
                h[q] = bf2f(Hb[(size_t)s[q] * 64 + lane]);
            }
            float mn = m;
#pragma unroll
            for (int q = 0; q < 8; q++) mn = fmaxf(mn, e[q]);
            const float scale = __expf(m - mn);
            float w[8];
#pragma unroll
            for (int q = 0; q < 8; q++) w[q] = __expf(e[q] - mn);
            float dsum = 0.f, hsum = 0.f;
#pragma unroll
            for (int q = 0; q < 8; q++) {
                dsum += w[q];
                hsum += w[q] * h[q];
            }
            denom = denom * scale + dsum;
            acc = acc * scale + hsum;
            m = mn;
        }
        for (; j + 4 <= je; j += 4) {
            int s[4];
#pragma unroll
            for (int q = 0; q < 4; q++) s[q] = col[j + q];
            float e[4], h[4];
#pragma unroll
            for (int q = 0; q < 4; q++) {
                float ev = sc_s[s[q]] + scd;
                e[q] = ev > 0.f ? ev : 0.2f * ev;
                h[q] = bf2f(Hb[(size_t)s[q] * 64 + lane]);
            }
            float mn = fmaxf(fmaxf(fmaxf(e[0], e[1]), fmaxf(e[2], e[3])), m);
            const float scale = __expf(m - mn);
            float dsum = 0.f, hsum = 0.f;
#pragma unroll
            for (int q = 0; q < 4; q++) {
                float wq = __expf(e[q] - mn);
                dsum += wq;
                hsum += wq * h[q];
            }
            denom = denom * scale + dsum;
            acc = acc * scale + hsum;
            m = mn;
        }
        for (; j < je; j++) {
            const int s0 = col[j];
            float e0 = sc_s[s0] + scd;
            e0 = e0 > 0.f ? e0 : 0.2f * e0;
            const float h0 = bf2f(Hb[(size_t)s0 * 64 + lane]);
            const float mn = fmaxf(e0, m);
            const float scale = __expf(m - mn);
            const float w0 = __expf(e0 - mn);
            denom = denom * scale + w0;
            acc = acc * scale + w0 * h0;
            m = mn;
        }
        float o = acc / denom + bl;
        if (RELU) o = o > 0.f ? o : 0.f;
        Out[(size_t)i * 64 + lane] = o;
    }
}

// ---------------- pooling (batch is sorted: run-length accumulate) ----------------

__global__ void pool_kernel(const float* __restrict__ H, const int* __restrict__ batch,
                            float* __restrict__ sums, int* __restrict__ cnts, int N) {
    const int CHUNK = 256;
    const int lane = threadIdx.x & 63;
    int gw = (blockIdx.x * blockDim.x + threadIdx.x) >> 6;
    const int nw = (gridDim.x * blockDim.x) >> 6;
    const int nchunks = (N + CHUNK - 1) / CHUNK;
    for (int c = gw; c < nchunks; c += nw) {
        const int lo = c * CHUNK;
        const int hi = min(lo + CHUNK, N);
        int curb = batch[lo];
        float acc = 0.f;
        int cnt = 0;
        for (int n = lo; n < hi; n++) {
            int b = batch[n];
            if (b != curb) {
                unsafeAtomicAdd(&sums[(size_t)curb * 64 + lane], acc);
                if (lane == 0) atomicAdd(&cnts[curb], cnt);
                acc = 0.f; cnt = 0; curb = b;
            }
            acc += H[(size_t)n * 64 + lane];
            cnt++;
        }
        unsafeAtomicAdd(&sums[(size_t)curb * 64 + lane], acc);
        if (lane == 0) atomicAdd(&cnts[curb], cnt);
    }
}

// ---------------- final MLP + log_softmax ----------------
__global__ void mlp_kernel(const float* __restrict__ sums, const int* __restrict__ cnts,
                           const float* __restrict__ lw, const float* __restrict__ lb,
                           const float* __restrict__ cw, const float* __restrict__ cb,
                           float* __restrict__ out) {
    __shared__ float gv[64];
    __shared__ float z[32];
    __shared__ float logits[6];
    const int g = blockIdx.x;
    const int t = threadIdx.x;

    float cnt = (float)cnts[g];
    cnt = cnt > 1.f ? cnt : 1.f;
    gv[t] = sums[(size_t)g * 64 + t] / cnt;
    __syncthreads();

    if (t < 32) {
        float acc = lb[t];
#pragma unroll
        for (int k = 0; k < 64; k++) acc += gv[k] * lw[k * 32 + t];
        z[t] = acc > 0.f ? acc : 0.f;
    }
    __syncthreads();
    if (t < 6) {
        float acc = cb[t];
#pragma unroll
        for (int k = 0; k < 32; k++) acc += z[k] * cw[k * 6 + t];
        logits[t] = acc;
    }
    __syncthreads();
    if (t == 0) {
        float m = logits[0];
#pragma unroll
        for (int i = 1; i < 6; i++) m = fmaxf(m, logits[i]);
        float s = 0.f;
#pragma unroll
        for (int i = 0; i < 6; i++) s += expf(logits[i] - m);
        float lse = m + logf(s);
#pragma unroll
        for (int i = 0; i < 6; i++) out[(size_t)g * 6 + i] = logits[i] - lse;
    }
}

// ---------------- launch ----------------

extern "C" void kernel_launch(void* const* d_in, const int* in_sizes, int n_in,
                              void* d_out, int out_size, void* d_ws, size_t ws_size,
                              hipStream_t stream) {
    const float* x    = (const float*)d_in[0];
    const int*   ei   = (const int*)d_in[1];
    const int*   batch= (const int*)d_in[2];
    const float* W1   = (const float*)d_in[3];
    const float* as1  = (const float*)d_in[4];
    const float* ad1  = (const float*)d_in[5];
    const float* b1   = (const float*)d_in[6];
    const float* W2   = (const float*)d_in[7];
    const float* as2  = (const float*)d_in[8];
    const float* ad2  = (const float*)d_in[9];
    const float* b2   = (const float*)d_in[10];
    const float* lw   = (const float*)d_in[11];
    const float* lb   = (const float*)d_in[12];
    const float* cw   = (const float*)d_in[13];
    const float* cb   = (const float*)d_in[14];
    float* out = (float*)d_out;

    const int N  = in_sizes[0] / 128;
    const int E  = in_sizes[1] / 2;
    const int G  = out_size / 6;
    const int NB = (N + BSZ - 1) / BSZ;

    char* ws = (char*)d_ws;
    size_t off = 0;
    auto alloc = [&](size_t bytes) {
        void* p = ws + off;
        off += (bytes + 255) & ~size_t(255);
        return p;
    };
    float*          hB     = (float*)alloc((size_t)N * 64 * 4);
    unsigned short* Hb     = (unsigned short*)alloc((size_t)N * 64 * 2);
    float*          sc_s   = (float*)alloc((size_t)N * 4);
    float*          sc_d   = (float*)alloc((size_t)N * 4);
    int*            rowptr = (int*)alloc((size_t)(N + 1) * 4);
    int*            colidx = (int*)alloc((size_t)E * 4);
    unsigned*       staged = (unsigned*)alloc((size_t)E * 4);
    int*            bhist  = (int*)alloc((size_t)256 * 4);
    int*            bbase  = (int*)alloc((size_t)257 * 4);
    int*            bcur   = (int*)alloc((size_t)256 * 4);
    float*          psum   = (float*)alloc((size_t)G * 64 * 4);
    int*            pcnt   = (int*)alloc((size_t)G * 4);
    (void)ws_size;

    const int TB = 256;
    const int gemm_grid = (N + 63) / 64;
    const int part_blocks = (E + CH - 1) / CH;

    // ---- CSR build by dst ----
    hipMemsetAsync(bhist, 0, 256 * 4, stream);
    bucket_hist_kernel<<<1024, TB, 0, stream>>>(ei + E, bhist, E);
    bucket_scan_kernel<<<1, 256, 0, stream>>>(bhist, bbase, bcur, NB, E);
    partition_kernel<<<part_blocks, 256, 0, stream>>>(ei, E, bcur, staged);
    place_kernel<<<NB, 256, 0, stream>>>(staged, bbase, rowptr, colidx, N, E, NB);

    // ---- layer 1 ----
    gat_gemm_kernel<128><<<gemm_grid, TB, 0, stream>>>(x, W1, as1, ad1, Hb, sc_s, sc_d, N);
    gat_fused_agg<true><<<2048, TB, 0, stream>>>(rowptr, colidx, sc_s, sc_d, Hb, b1, hB, N);

    // ---- layer 2 ----
    gat_gemm_kernel<64><<<gemm_grid, TB, 0, stream>>>(hB, W2, as2, ad2, Hb, sc_s, sc_d, N);
    gat_fused_agg<false><<<2048, TB, 0, stream>>>(rowptr, colidx, sc_s, sc_d, Hb, b2, hB, N);

    // ---- pooling + MLP head ----
    hipMemsetAsync(psum, 0, (size_t)G * 64 * 4, stream);
    hipMemsetAsync(pcnt, 0, (size_t)G * 4, stream);
    pool_kernel<<<128, TB, 0, stream>>>(hB, batch, psum, pcnt, N);
    mlp_kernel<<<G, 64, 0, stream>>>(psum, pcnt, lw, lb, cw, cb, out);
}

// Round 11
// 474.280 us; speedup vs baseline: 1.6328x; 1.1239x over previous
//
#include <hip/hip_runtime.h>

// ---------------- bf16 helpers ----------------

__device__ __forceinline__ unsigned short f2bf(float f) {
    unsigned u = __float_as_uint(f);
    unsigned r = (u + 0x7FFFu + ((u >> 16) & 1u)) >> 16;
    return (unsigned short)r;
}
__device__ __forceinline__ float bf2f(unsigned short u) {
    return __uint_as_float(((unsigned)u) << 16);
}

// ---------------- node GEMM + attention scores ----------------
template<int K>
__global__ __launch_bounds__(256, 2)
void gat_gemm_kernel(const float* __restrict__ X, const float* __restrict__ W,
                     const float* __restrict__ a_s, const float* __restrict__ a_d,
                     unsigned short* __restrict__ Hb, float* __restrict__ sc_s,
                     float* __restrict__ sc_d, int nrows) {
    __shared__ float Wl[K * 64];
    __shared__ float Xl[64 * K];

    const int tid = threadIdx.x;
    const int tile0 = blockIdx.x * 64;

    for (int i = tid; i < K * 64 / 4; i += 256)
        reinterpret_cast<float4*>(Wl)[i] = reinterpret_cast<const float4*>(W)[i];
    for (int i = tid; i < 64 * K / 4; i += 256) {
        const int row = i / (K / 4);
        const int gr = tile0 + row;
        float4 v = make_float4(0.f, 0.f, 0.f, 0.f);
        if (gr < nrows) v = reinterpret_cast<const float4*>(X)[(size_t)gr * (K / 4) + (i % (K / 4))];
        reinterpret_cast<float4*>(Xl)[i] = v;
    }
    __syncthreads();

    const int lane = tid & 63;
    const int wave = tid >> 6;
    const float asl = a_s[lane];
    const float adl = a_d[lane];

#pragma unroll
    for (int g = 0; g < 4; g++) {
        const int r0 = wave * 16 + g * 4;
        if (tile0 + r0 >= nrows) break;
        float acc0 = 0.f, acc1 = 0.f, acc2 = 0.f, acc3 = 0.f;
        const float* xp0 = Xl + (size_t)(r0 + 0) * K;
        const float* xp1 = Xl + (size_t)(r0 + 1) * K;
        const float* xp2 = Xl + (size_t)(r0 + 2) * K;
        const float* xp3 = Xl + (size_t)(r0 + 3) * K;
#pragma unroll 2
        for (int k = 0; k < K; k += 4) {
            const float4 a = *reinterpret_cast<const float4*>(xp0 + k);
            const float4 b = *reinterpret_cast<const float4*>(xp1 + k);
            const float4 c = *reinterpret_cast<const float4*>(xp2 + k);
            const float4 d = *reinterpret_cast<const float4*>(xp3 + k);
            const float w0 = Wl[(k + 0) * 64 + lane];
            const float w1 = Wl[(k + 1) * 64 + lane];
            const float w2 = Wl[(k + 2) * 64 + lane];
            const float w3 = Wl[(k + 3) * 64 + lane];
            acc0 += a.x * w0 + a.y * w1 + a.z * w2 + a.w * w3;
            acc1 += b.x * w0 + b.y * w1 + b.z * w2 + b.w * w3;
            acc2 += c.x * w0 + c.y * w1 + c.z * w2 + c.w * w3;
            acc3 += d.x * w0 + d.y * w1 + d.z * w2 + d.w * w3;
        }
        const float accs[4] = {acc0, acc1, acc2, acc3};
#pragma unroll
        for (int r = 0; r < 4; r++) {
            const int gr = tile0 + r0 + r;
            if (gr >= nrows) break;
            Hb[(size_t)gr * 64 + lane] = f2bf(accs[r]);
            float ps = accs[r] * asl;
            float pd = accs[r] * adl;
#pragma unroll
            for (int off = 32; off; off >>= 1) {
                ps += __shfl_down(ps, off);
                pd += __shfl_down(pd, off);
            }
            if (lane == 0) {
                sc_s[gr] = ps;
                sc_d[gr] = pd;
            }
        }
    }
}

// ---------------- CSR build: bucket hist -> bucket scan -> partition -> place
#define BSZ   512
#define NBITS 9
#define CH    4096

__global__ __launch_bounds__(256)
void bucket_hist_kernel(const int* __restrict__ dst, int* __restrict__ bhist, int E) {
    __shared__ int cnt[256];
    const int t = threadIdx.x;
    cnt[t] = 0;
    __syncthreads();
    const int tid = blockIdx.x * blockDim.x + t;
    const int stride = gridDim.x * blockDim.x;
    const int E4 = E >> 2;
    for (int i = tid; i < E4; i += stride) {
        const int4 d = reinterpret_cast<const int4*>(dst)[i];
        atomicAdd(&cnt[d.x >> NBITS], 1);
        atomicAdd(&cnt[d.y >> NBITS], 1);
        atomicAdd(&cnt[d.z >> NBITS], 1);
        atomicAdd(&cnt[d.w >> NBITS], 1);
    }
    for (int i = (E4 << 2) + tid; i < E; i += stride)
        atomicAdd(&cnt[dst[i] >> NBITS], 1);
    __syncthreads();
    if (cnt[t] > 0) atomicAdd(&bhist[t], cnt[t]);
}

__global__ void bucket_scan_kernel(const int* __restrict__ bhist, int* __restrict__ bbase,
                                   int* __restrict__ bcur, int NB, int E) {
    __shared__ int s[256];
    const int t = threadIdx.x;
    const int v = (t < NB) ? bhist[t] : 0;
    s[t] = v;
    __syncthreads();
    for (int off = 1; off < 256; off <<= 1) {
        int u = (t >= off) ? s[t - off] : 0;
        __syncthreads();
        s[t] += u;
        __syncthreads();
    }
    if (t < NB) {
        const int excl = s[t] - v;
        bbase[t] = excl;
        bcur[t] = excl;
    }
    if (t == 0) bbase[NB] = E;
}

__global__ __launch_bounds__(256)
void partition_kernel(const int* __restrict__ ei, int E,
                      int* __restrict__ bcur, unsigned* __restrict__ staged) {
    __shared__ int cnt[256], scantmp[256], excl[256], cnt2[256], gbase[256];
    __shared__ unsigned packed[CH];
    __shared__ unsigned char bid[CH];
    const int t = threadIdx.x;
    const int e0 = blockIdx.x * CH;

    cnt[t] = 0;
    cnt2[t] = 0;
    __syncthreads();

    unsigned pk[16];
    int bb[16];
#pragma unroll
    for (int i = 0; i < 16; i++) {
        const int e = e0 + i * 256 + t;
        if (e < E) {
            const int d = ei[E + e];
            const int s = ei[e];
            bb[i] = d >> NBITS;
            pk[i] = ((unsigned)(d & (BSZ - 1)) << 17) | (unsigned)s;
            atomicAdd(&cnt[bb[i]], 1);
        } else bb[i] = -1;
    }
    __syncthreads();

    int v = cnt[t];
    scantmp[t] = v;
    __syncthreads();
    for (int off = 1; off < 256; off <<= 1) {
        int u = (t >= off) ? scantmp[t - off] : 0;
        __syncthreads();
        scantmp[t] += u;
        __syncthreads();
    }
    excl[t] = scantmp[t] - v;
    if (v > 0) gbase[t] = atomicAdd(&bcur[t], v);
    __syncthreads();

#pragma unroll
    for (int i = 0; i < 16; i++) {
        if (bb[i] >= 0) {
            const int slot = atomicAdd(&cnt2[bb[i]], 1);
            const int p = excl[bb[i]] + slot;
            packed[p] = pk[i];
            bid[p] = (unsigned char)bb[i];
        }
    }
    __syncthreads();

    const int nvalid = min(CH, E - e0);
    for (int i = t; i < nvalid; i += 256) {
        const int b = bid[i];
        staged[gbase[b] + (i - excl[b])] = packed[i];
    }
}

__global__ __launch_bounds__(256)
void place_kernel(const unsigned* __restrict__ staged, const int* __restrict__ bbase,
                  int* __restrict__ rowptr, int* __restrict__ col, int N, int E, int NB) {
    __shared__ int nc[BSZ];
    __shared__ int rp[BSZ];
    __shared__ int pairs[256];
    const int b = blockIdx.x;
    const int n0 = b * BSZ;
    const int nn = min(BSZ, N - n0);
    const int t = threadIdx.x;

    nc[t] = 0;
    nc[t + 256] = 0;
    __syncthreads();

    const int lo = bbase[b];
    const int hi = bbase[b + 1];
    for (int e = lo + t; e < hi; e += 256)
        atomicAdd(&nc[staged[e] >> 17], 1);
    __syncthreads();

    const int c0 = nc[2 * t], c1 = nc[2 * t + 1];
    const int ps = c0 + c1;
    pairs[t] = ps;
    __syncthreads();
    for (int off = 1; off < 256; off <<= 1) {
        int u = (t >= off) ? pairs[t - off] : 0;
        __syncthreads();
        pairs[t] += u;
        __syncthreads();
    }
    const int pexcl = pairs[t] - ps;
    rp[2 * t]     = lo + pexcl;
    rp[2 * t + 1] = lo + pexcl + c0;
    nc[2 * t] = 0;
    nc[2 * t + 1] = 0;
    __syncthreads();

    for (int i = t; i < nn; i += 256) rowptr[n0 + i] = rp[i];
    if (b == NB - 1 && t == 0) rowptr[N] = E;

    for (int e = lo + t; e < hi; e += 256) {
        const unsigned p = staged[e];
        const int dlo = (int)(p >> 17);
        const int src = (int)(p & 0x1FFFFu);
        const int pos = rp[dlo] + atomicAdd(&nc[dlo], 1);
        col[pos] = src;
    }
}

// ---------------- fused per-node online-softmax aggregation ------------------
// Wave-parallel: 64-edge chunks. Phase 1: lane q owns edge q (coalesced col
// load, sc_s gather, leaky, shuffle max/sum reduce, ONE v_exp for 64 edges).
// Phase 2: readlane-broadcast (soff, w) -> scalar-base gather of Hb row + fma.
template<bool RELU>
__global__ void gat_fused_agg(const int* __restrict__ rowptr, const int* __restrict__ col,
                              const float* __restrict__ sc_s, const float* __restrict__ sc_d,
                              const unsigned short* __restrict__ Hb, const float* __restrict__ bias,
                              float* __restrict__ Out, int N) {
    const int lane = threadIdx.x & 63;
    int gw = (blockIdx.x * blockDim.x + threadIdx.x) >> 6;
    const int nw = (gridDim.x * blockDim.x) >> 6;
    const float bl = bias[lane];
    const char* hbl = (const char*)Hb + lane * 2;   // per-lane base into Hb

    for (int i = gw; i < N; i += nw) {
        const float scd = sc_d[i];
        float es = sc_s[i] + scd;
        es = es > 0.f ? es : 0.2f * es;   // self loop
        float m = es;
        float denom = 1.f;
        float acc = bf2f(Hb[(size_t)i * 64 + lane]);
        const int jb = rowptr[i], je = rowptr[i + 1];

        for (int j0 = jb; j0 < je; j0 += 64) {
            const int nj = min(64, je - j0);
            int soff = 0;
            float el = -1e30f;
            if (lane < nj) {
                const int sl = col[j0 + lane];       // coalesced
                soff = sl << 7;                      // byte offset of Hb row
                const float ev = sc_s[sl] + scd;     // per-lane gather
                el = ev > 0.f ? ev : 0.2f * ev;
            }
            // wave max
            float cm = el;
#pragma unroll
            for (int off = 32; off; off >>= 1) cm = fmaxf(cm, __shfl_xor(cm, off));
            const float mn = fmaxf(m, cm);
            // 64 edge weights in one exp
            float wl = (lane < nj) ? __expf(el - mn) : 0.f;
            float wsum = wl;
#pragma unroll
            for (int off = 32; off; off >>= 1) wsum += __shfl_xor(wsum, off);
            const float scale = __expf(m - mn);
            denom = denom * scale + wsum;
            acc *= scale;
            m = mn;

            const int wbits = __float_as_int(wl);
            float a0 = 0.f, a1 = 0.f, a2 = 0.f, a3 = 0.f;
            int q = 0;
            for (; q + 4 <= nj; q += 4) {
                const int o0 = __builtin_amdgcn_readlane(soff, q);
                const int o1 = __builtin_amdgcn_readlane(soff, q + 1);
                const int o2 = __builtin_amdgcn_readlane(soff, q + 2);
                const int o3 = __builtin_amdgcn_readlane(soff, q + 3);
                const float w0 = __int_as_float(__builtin_amdgcn_readlane(wbits, q));
                const float w1 = __int_as_float(__builtin_amdgcn_readlane(wbits, q + 1));
                const float w2 = __int_as_float(__builtin_amdgcn_readlane(wbits, q + 2));
                const float w3 = __int_as_float(__builtin_amdgcn_readlane(wbits, q + 3));
                const unsigned short h0 = *(const unsigned short*)(hbl + o0);
                const unsigned short h1 = *(const unsigned short*)(hbl + o1);
                const unsigned short h2 = *(const unsigned short*)(hbl + o2);
                const unsigned short h3 = *(const unsigned short*)(hbl + o3);
                a0 += w0 * bf2f(h0);
                a1 += w1 * bf2f(h1);
                a2 += w2 * bf2f(h2);
                a3 += w3 * bf2f(h3);
            }
            for (; q < nj; q++) {
                const int o0 = __builtin_amdgcn_readlane(soff, q);
                const float w0 = __int_as_float(__builtin_amdgcn_readlane(wbits, q));
                const unsigned short h0 = *(const unsigned short*)(hbl + o0);
                a0 += w0 * bf2f(h0);
            }
            acc += (a0 + a1) + (a2 + a3);
        }
        float o = acc / denom + bl;
        if (RELU) o = o > 0.f ? o : 0.f;
        Out[(size_t)i * 64 + lane] = o;
    }
}

// ---------------- pooling (batch is sorted: run-length accumulate) ----------------

__global__ void pool_kernel(const float* __restrict__ H, const int* __restrict__ batch,
                            float* __restrict__ sums, int* __restrict__ cnts, int N) {
    const int CHUNK = 256;
    const int lane = threadIdx.x & 63;
    int gw = (blockIdx.x * blockDim.x + threadIdx.x) >> 6;
    const int nw = (gridDim.x * blockDim.x) >> 6;
    const int nchunks = (N + CHUNK - 1) / CHUNK;
    for (int c = gw; c < nchunks; c += nw) {
        const int lo = c * CHUNK;
        const int hi = min(lo + CHUNK, N);
        int curb = batch[lo];
        float acc = 0.f;
        int cnt = 0;
        for (int n = lo; n < hi; n++) {
            int b = batch[n];
            if (b != curb) {
                unsafeAtomicAdd(&sums[(size_t)curb * 64 + lane], acc);
                if (lane == 0) atomicAdd(&cnts[curb], cnt);
                acc = 0.f; cnt = 0; curb = b;
            }
            acc += H[(size_t)n * 64 + lane];
            cnt++;
        }
        unsafeAtomicAdd(&sums[(size_t)curb * 64 + lane], acc);
        if (lane == 0) atomicAdd(&cnts[curb], cnt);
    }
}

// ---------------- final MLP + log_softmax ----------------
__global__ void mlp_kernel(const float* __restrict__ sums, const int* __restrict__ cnts,
                           const float* __restrict__ lw, const float* __restrict__ lb,
                           const float* __restrict__ cw, const float* __restrict__ cb,
                           float* __restrict__ out) {
    __shared__ float gv[64];
    __shared__ float z[32];
    __shared__ float logits[6];
    const int g = blockIdx.x;
    const int t = threadIdx.x;

    float cnt = (float)cnts[g];
    cnt = cnt > 1.f ? cnt : 1.f;
    gv[t] = sums[(size_t)g * 64 + t] / cnt;
    __syncthreads();

    if (t < 32) {
        float acc = lb[t];
#pragma unroll
        for (int k = 0; k < 64; k++) acc += gv[k] * lw[k * 32 + t];
        z[t] = acc > 0.f ? acc : 0.f;
    }
    __syncthreads();
    if (t < 6) {
        float acc = cb[t];
#pragma unroll
        for (int k = 0; k < 32; k++) acc += z[k] * cw[k * 6 + t];
        logits[t] = acc;
    }
    __syncthreads();
    if (t == 0) {
        float m = logits[0];
#pragma unroll
        for (int i = 1; i < 6; i++) m = fmaxf(m, logits[i]);
        float s = 0.f;
#pragma unroll
        for (int i = 0; i < 6; i++) s += expf(logits[i] - m);
        float lse = m + logf(s);
#pragma unroll
        for (int i = 0; i < 6; i++) out[(size_t)g * 6 + i] = logits[i] - lse;
    }
}

// ---------------- launch ----------------

extern "C" void kernel_launch(void* const* d_in, const int* in_sizes, int n_in,
                              void* d_out, int out_size, void* d_ws, size_t ws_size,
                              hipStream_t stream) {
    const float* x    = (const float*)d_in[0];
    const int*   ei   = (const int*)d_in[1];
    const int*   batch= (const int*)d_in[2];
    const float* W1   = (const float*)d_in[3];
    const float* as1  = (const float*)d_in[4];
    const float* ad1  = (const float*)d_in[5];
    const float* b1   = (const float*)d_in[6];
    const float* W2   = (const float*)d_in[7];
    const float* as2  = (const float*)d_in[8];
    const float* ad2  = (const float*)d_in[9];
    const float* b2   = (const float*)d_in[10];
    const float* lw   = (const float*)d_in[11];
    const float* lb   = (const float*)d_in[12];
    const float* cw   = (const float*)d_in[13];
    const float* cb   = (const float*)d_in[14];
    float* out = (float*)d_out;

    const int N  = in_sizes[0] / 128;
    const int E  = in_sizes[1] / 2;
    const int G  = out_size / 6;
    const int NB = (N + BSZ - 1) / BSZ;

    char* ws = (char*)d_ws;
    size_t off = 0;
    auto alloc = [&](size_t bytes) {
        void* p = ws + off;
        off += (bytes + 255) & ~size_t(255);
        return p;
    };
    float*          hB     = (float*)alloc((size_t)N * 64 * 4);
    unsigned short* Hb     = (unsigned short*)alloc((size_t)N * 64 * 2);
    float*          sc_s   = (float*)alloc((size_t)N * 4);
    float*          sc_d   = (float*)alloc((size_t)N * 4);
    int*            rowptr = (int*)alloc((size_t)(N + 1) * 4);
    int*            colidx = (int*)alloc((size_t)E * 4);
    unsigned*       staged = (unsigned*)alloc((size_t)E * 4);
    int*            bhist  = (int*)alloc((size_t)256 * 4);
    int*            bbase  = (int*)alloc((size_t)257 * 4);
    int*            bcur   = (int*)alloc((size_t)256 * 4);
    float*          psum   = (float*)alloc((size_t)G * 64 * 4);
    int*            pcnt   = (int*)alloc((size_t)G * 4);
    (void)ws_size;

    const int TB = 256;
    const int gemm_grid = (N + 63) / 64;
    const int part_blocks = (E + CH - 1) / CH;

    // ---- CSR build by dst ----
    hipMemsetAsync(bhist, 0, 256 * 4, stream);
    bucket_hist_kernel<<<1024, TB, 0, stream>>>(ei + E, bhist, E);
    bucket_scan_kernel<<<1, 256, 0, stream>>>(bhist, bbase, bcur, NB, E);
    partition_kernel<<<part_blocks, 256, 0, stream>>>(ei, E, bcur, staged);
    place_kernel<<<NB, 256, 0, stream>>>(staged, bbase, rowptr, colidx, N, E, NB);

    // ---- layer 1 ----
    gat_gemm_kernel<128><<<gemm_grid, TB, 0, stream>>>(x, W1, as1, ad1, Hb, sc_s, sc_d, N);
    gat_fused_agg<true><<<2048, TB, 0, stream>>>(rowptr, colidx, sc_s, sc_d, Hb, b1, hB, N);

    // ---- layer 2 ----
    gat_gemm_kernel<64><<<gemm_grid, TB, 0, stream>>>(hB, W2, as2, ad2, Hb, sc_s, sc_d, N);
    gat_fused_agg<false><<<2048, TB, 0, stream>>>(rowptr, colidx, sc_s, sc_d, Hb, b2, hB, N);

    // ---- pooling + MLP head ----
    hipMemsetAsync(psum, 0, (size_t)G * 64 * 4, stream);
    hipMemsetAsync(pcnt, 0, (size_t)G * 4, stream);
    pool_kernel<<<128, TB, 0, stream>>>(hB, batch, psum, pcnt, N);
    mlp_kernel<<<G, 64, 0, stream>>>(psum, pcnt, lw, lb, cw, cb, out);
}

// Round 12
// 387.110 us; speedup vs baseline: 2.0005x; 1.2252x over previous
//
#include <hip/hip_runtime.h>

// ---------------- bf16 helpers ----------------

__device__ __forceinline__ unsigned short f2bf(float f) {
    unsigned u = __float_as_uint(f);
    unsigned r = (u + 0x7FFFu + ((u >> 16) & 1u)) >> 16;
    return (unsigned short)r;
}
__device__ __forceinline__ float bf2f(unsigned short u) {
    return __uint_as_float(((unsigned)u) << 16);
}

typedef __attribute__((ext_vector_type(8))) short bf16x8;
typedef __attribute__((ext_vector_type(4))) float f32x4;
typedef __attribute__((ext_vector_type(8))) unsigned short u16x8;

// ---------------- node GEMM via MFMA + attention scores ----------------
// 64-row tile/block, 4 waves; wave w computes rows w*16..w*16+15 x all 64 cols.
// X staged to LDS bf16 with 16B-chunk XOR swizzle (conflict-free A reads);
// W staged chunk-transposed [(k>>3)][n][k&7] (B frag = one ds_read_b128).
// A frag: lane holds A[row=lane&15][k=(lane>>4)*8+i]; B: B[k=(lane>>4)*8+i][col=lane&15].
// C/D (verified m89): col=lane&15, row=(lane>>4)*4+reg.
template<int K, bool IN_BF16>
__global__ __launch_bounds__(256, 4)
void gat_gemm_mfma(const void* __restrict__ Xin, const float* __restrict__ W,
                   const float* __restrict__ a_s, const float* __restrict__ a_d,
                   unsigned short* __restrict__ Hb, float* __restrict__ sc_s,
                   float* __restrict__ sc_d, int nrows) {
    __shared__ unsigned short Xl[64 * K];
    __shared__ unsigned short Wt[K * 64];
    const int t = threadIdx.x;
    const int tile0 = blockIdx.x * 64;
    const int CPR = K / 8;                 // 16B chunks per row

    // ---- stage X (pad rows zero), swizzle chunk' = chunk ^ (row&7) ----
    for (int c = t; c < 64 * CPR; c += 256) {
        const int row = c / CPR;
        const int ch  = c % CPR;
        const int gr  = tile0 + row;
        u16x8 v;
        if (gr < nrows) {
            if (IN_BF16) {
                v = *reinterpret_cast<const u16x8*>((const unsigned short*)Xin + (size_t)gr * K + ch * 8);
            } else {
                const float* src = (const float*)Xin + (size_t)gr * K + ch * 8;
                const float4 f0 = *reinterpret_cast<const float4*>(src);
                const float4 f1 = *reinterpret_cast<const float4*>(src + 4);
                v[0] = f2bf(f0.x); v[1] = f2bf(f0.y); v[2] = f2bf(f0.z); v[3] = f2bf(f0.w);
                v[4] = f2bf(f1.x); v[5] = f2bf(f1.y); v[6] = f2bf(f1.z); v[7] = f2bf(f1.w);
            }
        } else {
#pragma unroll
            for (int i = 0; i < 8; i++) v[i] = 0;
        }
        *reinterpret_cast<u16x8*>(&Xl[row * K + ((ch * 8) ^ ((row & 7) << 3))]) = v;
    }
    // ---- stage W (global read coalesced: i = k*64+n) ----
    for (int i = t; i < K * 64; i += 256) {
        const int k = i >> 6;
        const int n = i & 63;
        Wt[((k >> 3) * 64 + n) * 8 + (k & 7)] = f2bf(W[i]);
    }
    __syncthreads();

    const int lane = t & 63;
    const int wave = t >> 6;
    const int lg = lane >> 4;              // k-group 0..3
    const int li = lane & 15;

    f32x4 acc[4] = {{0.f,0.f,0.f,0.f},{0.f,0.f,0.f,0.f},{0.f,0.f,0.f,0.f},{0.f,0.f,0.f,0.f}};
    const int r = wave * 16 + li;          // A row (local to tile)

#pragma unroll
    for (int s = 0; s < K / 32; s++) {
        const int acol = (s * 32 + lg * 8) ^ ((r & 7) << 3);
        const bf16x8 a = *reinterpret_cast<const bf16x8*>(&Xl[r * K + acol]);
#pragma unroll
        for (int ct = 0; ct < 4; ct++) {
            const bf16x8 b = *reinterpret_cast<const bf16x8*>(&Wt[((s * 4 + lg) * 64 + ct * 16 + li) * 8]);
            acc[ct] = __builtin_amdgcn_mfma_f32_16x16x32_bf16(a, b, acc[ct], 0, 0, 0);
        }
    }

    // ---- epilogue: Hb (bf16) + scores ----
    float asv[4], adv[4];
#pragma unroll
    for (int ct = 0; ct < 4; ct++) {
        asv[ct] = a_s[ct * 16 + li];
        adv[ct] = a_d[ct * 16 + li];
    }
#pragma unroll
    for (int reg = 0; reg < 4; reg++) {
        const int gr = tile0 + wave * 16 + lg * 4 + reg;
        float ps = 0.f, pd = 0.f;
        if (gr < nrows) {
#pragma unroll
            for (int ct = 0; ct < 4; ct++) {
                const float v = acc[ct][reg];
                Hb[(size_t)gr * 64 + ct * 16 + li] = f2bf(v);
                ps += v * asv[ct];
                pd += v * adv[ct];
            }
        }
#pragma unroll
        for (int off = 8; off; off >>= 1) {
            ps += __shfl_xor(ps, off);
            pd += __shfl_xor(pd, off);
        }
        if (li == 0 && gr < nrows) {
            sc_s[gr] = ps;
            sc_d[gr] = pd;
        }
    }
}

// ---------------- CSR build: bucket hist -> bucket scan -> partition -> place
#define BSZ   512
#define NBITS 9
#define CH    4096

__global__ __launch_bounds__(256)
void bucket_hist_kernel(const int* __restrict__ dst, int* __restrict__ bhist, int E) {
    __shared__ int cnt[256];
    const int t = threadIdx.x;
    cnt[t] = 0;
    __syncthreads();
    const int tid = blockIdx.x * blockDim.x + t;
    const int stride = gridDim.x * blockDim.x;
    const int E4 = E >> 2;
    for (int i = tid; i < E4; i += stride) {
        const int4 d = reinterpret_cast<const int4*>(dst)[i];
        atomicAdd(&cnt[d.x >> NBITS], 1);
        atomicAdd(&cnt[d.y >> NBITS], 1);
        atomicAdd(&cnt[d.z >> NBITS], 1);
        atomicAdd(&cnt[d.w >> NBITS], 1);
    }
    for (int i = (E4 << 2) + tid; i < E; i += stride)
        atomicAdd(&cnt[dst[i] >> NBITS], 1);
    __syncthreads();
    if (cnt[t] > 0) atomicAdd(&bhist[t], cnt[t]);
}

__global__ void bucket_scan_kernel(const int* __restrict__ bhist, int* __restrict__ bbase,
                                   int* __restrict__ bcur, int NB, int E) {
    __shared__ int s[256];
    const int t = threadIdx.x;
    const int v = (t < NB) ? bhist[t] : 0;
    s[t] = v;
    __syncthreads();
    for (int off = 1; off < 256; off <<= 1) {
        int u = (t >= off) ? s[t - off] : 0;
        __syncthreads();
        s[t] += u;
        __syncthreads();
    }
    if (t < NB) {
        const int excl = s[t] - v;
        bbase[t] = excl;
        bcur[t] = excl;
    }
    if (t == 0) bbase[NB] = E;
}

__global__ __launch_bounds__(256)
void partition_kernel(const int* __restrict__ ei, int E,
                      int* __restrict__ bcur, unsigned* __restrict__ staged) {
    __shared__ int cnt[256], scantmp[256], excl[256], cnt2[256], gbase[256];
    __shared__ unsigned packed[CH];
    __shared__ unsigned char bid[CH];
    const int t = threadIdx.x;
    const int e0 = blockIdx.x * CH;

    cnt[t] = 0;
    cnt2[t] = 0;
    __syncthreads();

    unsigned pk[16];
    int bb[16];
#pragma unroll
    for (int i = 0; i < 16; i++) {
        const int e = e0 + i * 256 + t;
        if (e < E) {
            const int d = ei[E + e];
            const int s = ei[e];
            bb[i] = d >> NBITS;
            pk[i] = ((unsigned)(d & (BSZ - 1)) << 17) | (unsigned)s;
            atomicAdd(&cnt[bb[i]], 1);
        } else bb[i] = -1;
    }
    __syncthreads();

    int v = cnt[t];
    scantmp[t] = v;
    __syncthreads();
    for (int off = 1; off < 256; off <<= 1) {
        int u = (t >= off) ? scantmp[t - off] : 0;
        __syncthreads();
        scantmp[t] += u;
        __syncthreads();
    }
    excl[t] = scantmp[t] - v;
    if (v > 0) gbase[t] = atomicAdd(&bcur[t], v);
    __syncthreads();

#pragma unroll
    for (int i = 0; i < 16; i++) {
        if (bb[i] >= 0) {
            const int slot = atomicAdd(&cnt2[bb[i]], 1);
            const int p = excl[bb[i]] + slot;
            packed[p] = pk[i];
            bid[p] = (unsigned char)bb[i];
        }
    }
    __syncthreads();

    const int nvalid = min(CH, E - e0);
    for (int i = t; i < nvalid; i += 256) {
        const int b = bid[i];
        staged[gbase[b] + (i - excl[b])] = packed[i];
    }
}

__global__ __launch_bounds__(256)
void place_kernel(const unsigned* __restrict__ staged, const int* __restrict__ bbase,
                  int* __restrict__ rowptr, int* __restrict__ col, int N, int E, int NB) {
    __shared__ int nc[BSZ];
    __shared__ int rp[BSZ];
    __shared__ int pairs[256];
    const int b = blockIdx.x;
    const int n0 = b * BSZ;
    const int nn = min(BSZ, N - n0);
    const int t = threadIdx.x;

    nc[t] = 0;
    nc[t + 256] = 0;
    __syncthreads();

    const int lo = bbase[b];
    const int hi = bbase[b + 1];
    for (int e = lo + t; e < hi; e += 256)
        atomicAdd(&nc[staged[e] >> 17], 1);
    __syncthreads();

    const int c0 = nc[2 * t], c1 = nc[2 * t + 1];
    const int ps = c0 + c1;
    pairs[t] = ps;
    __syncthreads();
    for (int off = 1; off < 256; off <<= 1) {
        int u = (t >= off) ? pairs[t - off] : 0;
        __syncthreads();
        pairs[t] += u;
        __syncthreads();
    }
    const int pexcl = pairs[t] - ps;
    rp[2 * t]     = lo + pexcl;
    rp[2 * t + 1] = lo + pexcl + c0;
    nc[2 * t] = 0;
    nc[2 * t + 1] = 0;
    __syncthreads();

    for (int i = t; i < nn; i += 256) rowptr[n0 + i] = rp[i];
    if (b == NB - 1 && t == 0) rowptr[N] = E;

    for (int e = lo + t; e < hi; e += 256) {
        const unsigned p = staged[e];
        const int dlo = (int)(p >> 17);
        const int src = (int)(p & 0x1FFFFu);
        const int pos = rp[dlo] + atomicAdd(&nc[dlo], 1);
        col[pos] = src;
    }
}

// ---------------- fused per-node online-softmax aggregation ------------------
// Wave-parallel: 64-edge chunks; phase 1 softmax owned per-lane, phase 2
// readlane-broadcast scalar-base gather of Hb rows. OUTBF writes bf16.
template<bool RELU, bool OUTBF>
__global__ void gat_fused_agg(const int* __restrict__ rowptr, const int* __restrict__ col,
                              const float* __restrict__ sc_s, const float* __restrict__ sc_d,
                              const unsigned short* __restrict__ Hb, const float* __restrict__ bias,
                              void* __restrict__ Out, int N) {
    const int lane = threadIdx.x & 63;
    int gw = (blockIdx.x * blockDim.x + threadIdx.x) >> 6;
    const int nw = (gridDim.x * blockDim.x) >> 6;
    const float bl = bias[lane];
    const char* hbl = (const char*)Hb + lane * 2;

    for (int i = gw; i < N; i += nw) {
        const float scd = sc_d[i];
        float es = sc_s[i] + scd;
        es = es > 0.f ? es : 0.2f * es;   // self loop
        float m = es;
        float denom = 1.f;
        float acc = bf2f(Hb[(size_t)i * 64 + lane]);
        const int jb = rowptr[i], je = rowptr[i + 1];

        for (int j0 = jb; j0 < je; j0 += 64) {
            const int nj = min(64, je - j0);
            int soff = 0;
            float el = -1e30f;
            if (lane < nj) {
                const int sl = col[j0 + lane];
                soff = sl << 7;
                const float ev = sc_s[sl] + scd;
                el = ev > 0.f ? ev : 0.2f * ev;
            }
            float cm = el;
#pragma unroll
            for (int off = 32; off; off >>= 1) cm = fmaxf(cm, __shfl_xor(cm, off));
            const float mn = fmaxf(m, cm);
            float wl = (lane < nj) ? __expf(el - mn) : 0.f;
            float wsum = wl;
#pragma unroll
            for (int off = 32; off; off >>= 1) wsum += __shfl_xor(wsum, off);
            const float scale = __expf(m - mn);
            denom = denom * scale + wsum;
            acc *= scale;
            m = mn;

            const int wbits = __float_as_int(wl);
            float a0 = 0.f, a1 = 0.f, a2 = 0.f, a3 = 0.f;
            int q = 0;
            for (; q + 4 <= nj; q += 4) {
                const int o0 = __builtin_amdgcn_readlane(soff, q);
                const int o1 = __builtin_amdgcn_readlane(soff, q + 1);
                const int o2 = __builtin_amdgcn_readlane(soff, q + 2);
                const int o3 = __builtin_amdgcn_readlane(soff, q + 3);
                const float w0 = __int_as_float(__builtin_amdgcn_readlane(wbits, q));
                const float w1 = __int_as_float(__builtin_amdgcn_readlane(wbits, q + 1));
                const float w2 = __int_as_float(__builtin_amdgcn_readlane(wbits, q + 2));
                const float w3 = __int_as_float(__builtin_amdgcn_readlane(wbits, q + 3));
                const unsigned short h0 = *(const unsigned short*)(hbl + o0);
                const unsigned short h1 = *(const unsigned short*)(hbl + o1);
                const unsigned short h2 = *(const unsigned short*)(hbl + o2);
                const unsigned short h3 = *(const unsigned short*)(hbl + o3);
                a0 += w0 * bf2f(h0);
                a1 += w1 * bf2f(h1);
                a2 += w2 * bf2f(h2);
                a3 += w3 * bf2f(h3);
            }
            for (; q < nj; q++) {
                const int o0 = __builtin_amdgcn_readlane(soff, q);
                const float w0 = __int_as_float(__builtin_amdgcn_readlane(wbits, q));
                const unsigned short h0 = *(const unsigned short*)(hbl + o0);
                a0 += w0 * bf2f(h0);
            }
            acc += (a0 + a1) + (a2 + a3);
        }
        float o = acc / denom + bl;
        if (RELU) o = o > 0.f ? o : 0.f;
        if (OUTBF) ((unsigned short*)Out)[(size_t)i * 64 + lane] = f2bf(o);
        else       ((float*)Out)[(size_t)i * 64 + lane] = o;
    }
}

// ---------------- pooling (batch is sorted: run-length accumulate) ----------------

__global__ void pool_kernel(const float* __restrict__ H, const int* __restrict__ batch,
                            float* __restrict__ sums, int* __restrict__ cnts, int N) {
    const int CHUNK = 256;
    const int lane = threadIdx.x & 63;
    int gw = (blockIdx.x * blockDim.x + threadIdx.x) >> 6;
    const int nw = (gridDim.x * blockDim.x) >> 6;
    const int nchunks = (N + CHUNK - 1) / CHUNK;
    for (int c = gw; c < nchunks; c += nw) {
        const int lo = c * CHUNK;
        const int hi = min(lo + CHUNK, N);
        int curb = batch[lo];
        float acc = 0.f;
        int cnt = 0;
        for (int n = lo; n < hi; n++) {
            int b = batch[n];
            if (b != curb) {
                unsafeAtomicAdd(&sums[(size_t)curb * 64 + lane], acc);
                if (lane == 0) atomicAdd(&cnts[curb], cnt);
                acc = 0.f; cnt = 0; curb = b;
            }
            acc += H[(size_t)n * 64 + lane];
            cnt++;
        }
        unsafeAtomicAdd(&sums[(size_t)curb * 64 + lane], acc);
        if (lane == 0) atomicAdd(&cnts[curb], cnt);
    }
}

// ---------------- final MLP + log_softmax ----------------
__global__ void mlp_kernel(const float* __restrict__ sums, const int* __restrict__ cnts,
                           const float* __restrict__ lw, const float* __restrict__ lb,
                           const float* __restrict__ cw, const float* __restrict__ cb,
                           float* __restrict__ out) {
    __shared__ float gv[64];
    __shared__ float z[32];
    __shared__ float logits[6];
    const int g = blockIdx.x;
    const int t = threadIdx.x;

    float cnt = (float)cnts[g];
    cnt = cnt > 1.f ? cnt : 1.f;
    gv[t] = sums[(size_t)g * 64 + t] / cnt;
    __syncthreads();

    if (t < 32) {
        float acc = lb[t];
#pragma unroll
        for (int k = 0; k < 64; k++) acc += gv[k] * lw[k * 32 + t];
        z[t] = acc > 0.f ? acc : 0.f;
    }
    __syncthreads();
    if (t < 6) {
        float acc = cb[t];
#pragma unroll
        for (int k = 0; k < 32; k++) acc += z[k] * cw[k * 6 + t];
        logits[t] = acc;
    }
    __syncthreads();
    if (t == 0) {
        float m = logits[0];
#pragma unroll
        for (int i = 1; i < 6; i++) m = fmaxf(m, logits[i]);
        float s = 0.f;
#pragma unroll
        for (int i = 0; i < 6; i++) s += expf(logits[i] - m);
        float lse = m + logf(s);
#pragma unroll
        for (int i = 0; i < 6; i++) out[(size_t)g * 6 + i] = logits[i] - lse;
    }
}

// ---------------- launch ----------------

extern "C" void kernel_launch(void* const* d_in, const int* in_sizes, int n_in,
                              void* d_out, int out_size, void* d_ws, size_t ws_size,
                              hipStream_t stream) {
    const float* x    = (const float*)d_in[0];
    const int*   ei   = (const int*)d_in[1];
    const int*   batch= (const int*)d_in[2];
    const float* W1   = (const float*)d_in[3];
    const float* as1  = (const float*)d_in[4];
    const float* ad1  = (const float*)d_in[5];
    const float* b1   = (const float*)d_in[6];
    const float* W2   = (const float*)d_in[7];
    const float* as2  = (const float*)d_in[8];
    const float* ad2  = (const float*)d_in[9];
    const float* b2   = (const float*)d_in[10];
    const float* lw   = (const float*)d_in[11];
    const float* lb   = (const float*)d_in[12];
    const float* cw   = (const float*)d_in[13];
    const float* cb   = (const float*)d_in[14];
    float* out = (float*)d_out;

    const int N  = in_sizes[0] / 128;
    const int E  = in_sizes[1] / 2;
    const int G  = out_size / 6;
    const int NB = (N + BSZ - 1) / BSZ;

    char* ws = (char*)d_ws;
    size_t off = 0;
    auto alloc = [&](size_t bytes) {
        void* p = ws + off;
        off += (bytes + 255) & ~size_t(255);
        return p;
    };
    float*          hB     = (float*)alloc((size_t)N * 64 * 4);          // layer2 agg out (f32)
    unsigned short* hB1b   = (unsigned short*)alloc((size_t)N * 64 * 2); // layer1 agg out (bf16)
    unsigned short* Hb     = (unsigned short*)alloc((size_t)N * 64 * 2); // GEMM out (bf16)
    float*          sc_s   = (float*)alloc((size_t)N * 4);
    float*          sc_d   = (float*)alloc((size_t)N * 4);
    int*            rowptr = (int*)alloc((size_t)(N + 1) * 4);
    int*            colidx = (int*)alloc((size_t)E * 4);
    unsigned*       staged = (unsigned*)alloc((size_t)E * 4);
    int*            bhist  = (int*)alloc((size_t)256 * 4);
    int*            bbase  = (int*)alloc((size_t)257 * 4);
    int*            bcur   = (int*)alloc((size_t)256 * 4);
    float*          psum   = (float*)alloc((size_t)G * 64 * 4);
    int*            pcnt   = (int*)alloc((size_t)G * 4);
    (void)ws_size;

    const int TB = 256;
    const int gemm_grid = (N + 63) / 64;
    const int part_blocks = (E + CH - 1) / CH;

    // ---- CSR build by dst ----
    hipMemsetAsync(bhist, 0, 256 * 4, stream);
    bucket_hist_kernel<<<1024, TB, 0, stream>>>(ei + E, bhist, E);
    bucket_scan_kernel<<<1, 256, 0, stream>>>(bhist, bbase, bcur, NB, E);
    partition_kernel<<<part_blocks, 256, 0, stream>>>(ei, E, bcur, staged);
    place_kernel<<<NB, 256, 0, stream>>>(staged, bbase, rowptr, colidx, N, E, NB);

    // ---- layer 1 ----
    gat_gemm_mfma<128, false><<<gemm_grid, TB, 0, stream>>>(x, W1, as1, ad1, Hb, sc_s, sc_d, N);
    gat_fused_agg<true, true><<<2048, TB, 0, stream>>>(rowptr, colidx, sc_s, sc_d, Hb, b1, hB1b, N);

    // ---- layer 2 ----
    gat_gemm_mfma<64, true><<<gemm_grid, TB, 0, stream>>>(hB1b, W2, as2, ad2, Hb, sc_s, sc_d, N);
    gat_fused_agg<false, false><<<2048, TB, 0, stream>>>(rowptr, colidx, sc_s, sc_d, Hb, b2, hB, N);

    // ---- pooling + MLP head ----
    hipMemsetAsync(psum, 0, (size_t)G * 64 * 4, stream);
    hipMemsetAsync(pcnt, 0, (size_t)G * 4, stream);
    pool_kernel<<<128, TB, 0, stream>>>(hB, batch, psum, pcnt, N);
    mlp_kernel<<<G, 64, 0, stream>>>(psum, pcnt, lw, lb, cw, cb, out);
}

// Round 13
// 374.039 us; speedup vs baseline: 2.0704x; 1.0349x over previous
//
#include <hip/hip_runtime.h>

// ---------------- bf16 helpers ----------------

__device__ __forceinline__ unsigned short f2bf(float f) {
    unsigned u = __float_as_uint(f);
    unsigned r = (u + 0x7FFFu + ((u >> 16) & 1u)) >> 16;
    return (unsigned short)r;
}
__device__ __forceinline__ float bf2f(unsigned short u) {
    return __uint_as_float(((unsigned)u) << 16);
}

typedef __attribute__((ext_vector_type(8))) short bf16x8;
typedef __attribute__((ext_vector_type(4))) float f32x4;
typedef __attribute__((ext_vector_type(8))) unsigned short u16x8;

// ---------------- node GEMM via MFMA + attention scores ----------------
template<int K, bool IN_BF16>
__global__ __launch_bounds__(256, 4)
void gat_gemm_mfma(const void* __restrict__ Xin, const float* __restrict__ W,
                   const float* __restrict__ a_s, const float* __restrict__ a_d,
                   unsigned short* __restrict__ Hb, float* __restrict__ sc_s,
                   float* __restrict__ sc_d, int nrows) {
    __shared__ unsigned short Xl[64 * K];
    __shared__ unsigned short Wt[K * 64];
    const int t = threadIdx.x;
    const int tile0 = blockIdx.x * 64;
    const int CPR = K / 8;

    for (int c = t; c < 64 * CPR; c += 256) {
        const int row = c / CPR;
        const int ch  = c % CPR;
        const int gr  = tile0 + row;
        u16x8 v;
        if (gr < nrows) {
            if (IN_BF16) {
                v = *reinterpret_cast<const u16x8*>((const unsigned short*)Xin + (size_t)gr * K + ch * 8);
            } else {
                const float* src = (const float*)Xin + (size_t)gr * K + ch * 8;
                const float4 f0 = *reinterpret_cast<const float4*>(src);
                const float4 f1 = *reinterpret_cast<const float4*>(src + 4);
                v[0] = f2bf(f0.x); v[1] = f2bf(f0.y); v[2] = f2bf(f0.z); v[3] = f2bf(f0.w);
                v[4] = f2bf(f1.x); v[5] = f2bf(f1.y); v[6] = f2bf(f1.z); v[7] = f2bf(f1.w);
            }
        } else {
#pragma unroll
            for (int i = 0; i < 8; i++) v[i] = 0;
        }
        *reinterpret_cast<u16x8*>(&Xl[row * K + ((ch * 8) ^ ((row & 7) << 3))]) = v;
    }
    for (int i = t; i < K * 64; i += 256) {
        const int k = i >> 6;
        const int n = i & 63;
        Wt[((k >> 3) * 64 + n) * 8 + (k & 7)] = f2bf(W[i]);
    }
    __syncthreads();

    const int lane = t & 63;
    const int wave = t >> 6;
    const int lg = lane >> 4;
    const int li = lane & 15;

    f32x4 acc[4] = {{0.f,0.f,0.f,0.f},{0.f,0.f,0.f,0.f},{0.f,0.f,0.f,0.f},{0.f,0.f,0.f,0.f}};
    const int r = wave * 16 + li;

#pragma unroll
    for (int s = 0; s < K / 32; s++) {
        const int acol = (s * 32 + lg * 8) ^ ((r & 7) << 3);
        const bf16x8 a = *reinterpret_cast<const bf16x8*>(&Xl[r * K + acol]);
#pragma unroll
        for (int ct = 0; ct < 4; ct++) {
            const bf16x8 b = *reinterpret_cast<const bf16x8*>(&Wt[((s * 4 + lg) * 64 + ct * 16 + li) * 8]);
            acc[ct] = __builtin_amdgcn_mfma_f32_16x16x32_bf16(a, b, acc[ct], 0, 0, 0);
        }
    }

    float asv[4], adv[4];
#pragma unroll
    for (int ct = 0; ct < 4; ct++) {
        asv[ct] = a_s[ct * 16 + li];
        adv[ct] = a_d[ct * 16 + li];
    }
#pragma unroll
    for (int reg = 0; reg < 4; reg++) {
        const int gr = tile0 + wave * 16 + lg * 4 + reg;
        float ps = 0.f, pd = 0.f;
        if (gr < nrows) {
#pragma unroll
            for (int ct = 0; ct < 4; ct++) {
                const float v = acc[ct][reg];
                Hb[(size_t)gr * 64 + ct * 16 + li] = f2bf(v);
                ps += v * asv[ct];
                pd += v * adv[ct];
            }
        }
#pragma unroll
        for (int off = 8; off; off >>= 1) {
            ps += __shfl_xor(ps, off);
            pd += __shfl_xor(pd, off);
        }
        if (li == 0 && gr < nrows) {
            sc_s[gr] = ps;
            sc_d[gr] = pd;
        }
    }
}

// ---------------- CSR build: bucket hist -> bucket scan -> partition -> place
#define BSZ   512
#define NBITS 9
#define CH    4096

__global__ __launch_bounds__(256)
void bucket_hist_kernel(const int* __restrict__ dst, int* __restrict__ bhist, int E) {
    __shared__ int cnt[256];
    const int t = threadIdx.x;
    cnt[t] = 0;
    __syncthreads();
    const int tid = blockIdx.x * blockDim.x + t;
    const int stride = gridDim.x * blockDim.x;
    const int E4 = E >> 2;
    for (int i = tid; i < E4; i += stride) {
        const int4 d = reinterpret_cast<const int4*>(dst)[i];
        atomicAdd(&cnt[d.x >> NBITS], 1);
        atomicAdd(&cnt[d.y >> NBITS], 1);
        atomicAdd(&cnt[d.z >> NBITS], 1);
        atomicAdd(&cnt[d.w >> NBITS], 1);
    }
    for (int i = (E4 << 2) + tid; i < E; i += stride)
        atomicAdd(&cnt[dst[i] >> NBITS], 1);
    __syncthreads();
    if (cnt[t] > 0) atomicAdd(&bhist[t], cnt[t]);
}

__global__ void bucket_scan_kernel(const int* __restrict__ bhist, int* __restrict__ bbase,
                                   int* __restrict__ bcur, int NB, int E) {
    __shared__ int s[256];
    const int t = threadIdx.x;
    const int v = (t < NB) ? bhist[t] : 0;
    s[t] = v;
    __syncthreads();
    for (int off = 1; off < 256; off <<= 1) {
        int u = (t >= off) ? s[t - off] : 0;
        __syncthreads();
        s[t] += u;
        __syncthreads();
    }
    if (t < NB) {
        const int excl = s[t] - v;
        bbase[t] = excl;
        bcur[t] = excl;
    }
    if (t == 0) bbase[NB] = E;
}

__global__ __launch_bounds__(256)
void partition_kernel(const int* __restrict__ ei, int E,
                      int* __restrict__ bcur, unsigned* __restrict__ staged) {
    __shared__ int cnt[256], scantmp[256], excl[256], cnt2[256], gbase[256];
    __shared__ unsigned packed[CH];
    __shared__ unsigned char bid[CH];
    const int t = threadIdx.x;
    const int e0 = blockIdx.x * CH;

    cnt[t] = 0;
    cnt2[t] = 0;
    __syncthreads();

    unsigned pk[16];
    int bb[16];
#pragma unroll
    for (int i = 0; i < 16; i++) {
        const int e = e0 + i * 256 + t;
        if (e < E) {
            const int d = ei[E + e];
            const int s = ei[e];
            bb[i] = d >> NBITS;
            pk[i] = ((unsigned)(d & (BSZ - 1)) << 17) | (unsigned)s;
            atomicAdd(&cnt[bb[i]], 1);
        } else bb[i] = -1;
    }
    __syncthreads();

    int v = cnt[t];
    scantmp[t] = v;
    __syncthreads();
    for (int off = 1; off < 256; off <<= 1) {
        int u = (t >= off) ? scantmp[t - off] : 0;
        __syncthreads();
        scantmp[t] += u;
        __syncthreads();
    }
    excl[t] = scantmp[t] - v;
    if (v > 0) gbase[t] = atomicAdd(&bcur[t], v);
    __syncthreads();

#pragma unroll
    for (int i = 0; i < 16; i++) {
        if (bb[i] >= 0) {
            const int slot = atomicAdd(&cnt2[bb[i]], 1);
            const int p = excl[bb[i]] + slot;
            packed[p] = pk[i];
            bid[p] = (unsigned char)bb[i];
        }
    }
    __syncthreads();

    const int nvalid = min(CH, E - e0);
    for (int i = t; i < nvalid; i += 256) {
        const int b = bid[i];
        staged[gbase[b] + (i - excl[b])] = packed[i];
    }
}

__global__ __launch_bounds__(256)
void place_kernel(const unsigned* __restrict__ staged, const int* __restrict__ bbase,
                  int* __restrict__ rowptr, int* __restrict__ col, int N, int E, int NB) {
    __shared__ int nc[BSZ];
    __shared__ int rp[BSZ];
    __shared__ int pairs[256];
    const int b = blockIdx.x;
    const int n0 = b * BSZ;
    const int nn = min(BSZ, N - n0);
    const int t = threadIdx.x;

    nc[t] = 0;
    nc[t + 256] = 0;
    __syncthreads();

    const int lo = bbase[b];
    const int hi = bbase[b + 1];
    for (int e = lo + t; e < hi; e += 256)
        atomicAdd(&nc[staged[e] >> 17], 1);
    __syncthreads();

    const int c0 = nc[2 * t], c1 = nc[2 * t + 1];
    const int ps = c0 + c1;
    pairs[t] = ps;
    __syncthreads();
    for (int off = 1; off < 256; off <<= 1) {
        int u = (t >= off) ? pairs[t - off] : 0;
        __syncthreads();
        pairs[t] += u;
        __syncthreads();
    }
    const int pexcl = pairs[t] - ps;
    rp[2 * t]     = lo + pexcl;
    rp[2 * t + 1] = lo + pexcl + c0;
    nc[2 * t] = 0;
    nc[2 * t + 1] = 0;
    __syncthreads();

    for (int i = t; i < nn; i += 256) rowptr[n0 + i] = rp[i];
    if (b == NB - 1 && t == 0) rowptr[N] = E;

    for (int e = lo + t; e < hi; e += 256) {
        const unsigned p = staged[e];
        const int dlo = (int)(p >> 17);
        const int src = (int)(p & 0x1FFFFu);
        const int pos = rp[dlo] + atomicAdd(&nc[dlo], 1);
        col[pos] = src;
    }
}

// ---------------- fused per-node online-softmax aggregation ------------------
// Wave-parallel softmax; phase 2 = 8 independent readlane->broadcast-load chains.
template<bool RELU, bool OUTBF>
__global__ void gat_fused_agg(const int* __restrict__ rowptr, const int* __restrict__ col,
                              const float* __restrict__ sc_s, const float* __restrict__ sc_d,
                              const unsigned short* __restrict__ Hb, const float* __restrict__ bias,
                              void* __restrict__ Out, int N) {
    const int lane = threadIdx.x & 63;
    int gw = (blockIdx.x * blockDim.x + threadIdx.x) >> 6;
    const int nw = (gridDim.x * blockDim.x) >> 6;
    const float bl = bias[lane];
    const char* hbl = (const char*)Hb + lane * 2;

    for (int i = gw; i < N; i += nw) {
        const float scd = sc_d[i];
        float es = sc_s[i] + scd;
        es = es > 0.f ? es : 0.2f * es;   // self loop
        float m = es;
        float denom = 1.f;
        float acc = bf2f(Hb[(size_t)i * 64 + lane]);
        const int jb = rowptr[i], je = rowptr[i + 1];

        for (int j0 = jb; j0 < je; j0 += 64) {
            const int nj = min(64, je - j0);
            int soff = 0;
            float el = -1e30f;
            if (lane < nj) {
                const int sl = col[j0 + lane];
                soff = sl << 7;
                const float ev = sc_s[sl] + scd;
                el = ev > 0.f ? ev : 0.2f * ev;
            }
            float cm = el;
#pragma unroll
            for (int off = 32; off; off >>= 1) cm = fmaxf(cm, __shfl_xor(cm, off));
            const float mn = fmaxf(m, cm);
            float wl = (lane < nj) ? __expf(el - mn) : 0.f;
            float wsum = wl;
#pragma unroll
            for (int off = 32; off; off >>= 1) wsum += __shfl_xor(wsum, off);
            const float scale = __expf(m - mn);
            denom = denom * scale + wsum;
            acc *= scale;
            m = mn;

            const int wbits = __float_as_int(wl);
            float a0 = 0.f, a1 = 0.f, a2 = 0.f, a3 = 0.f;
            float a4 = 0.f, a5 = 0.f, a6 = 0.f, a7 = 0.f;
            int q = 0;
            for (; q + 8 <= nj; q += 8) {
                int o[8];
                float w[8];
                unsigned short h[8];
#pragma unroll
                for (int k = 0; k < 8; k++) {
                    o[k] = __builtin_amdgcn_readlane(soff, q + k);
                    w[k] = __int_as_float(__builtin_amdgcn_readlane(wbits, q + k));
                }
#pragma unroll
                for (int k = 0; k < 8; k++) h[k] = *(const unsigned short*)(hbl + o[k]);
                a0 += w[0] * bf2f(h[0]);
                a1 += w[1] * bf2f(h[1]);
                a2 += w[2] * bf2f(h[2]);
                a3 += w[3] * bf2f(h[3]);
                a4 += w[4] * bf2f(h[4]);
                a5 += w[5] * bf2f(h[5]);
                a6 += w[6] * bf2f(h[6]);
                a7 += w[7] * bf2f(h[7]);
            }
            for (; q + 4 <= nj; q += 4) {
                int o[4];
                float w[4];
                unsigned short h[4];
#pragma unroll
                for (int k = 0; k < 4; k++) {
                    o[k] = __builtin_amdgcn_readlane(soff, q + k);
                    w[k] = __int_as_float(__builtin_amdgcn_readlane(wbits, q + k));
                }
#pragma unroll
                for (int k = 0; k < 4; k++) h[k] = *(const unsigned short*)(hbl + o[k]);
                a0 += w[0] * bf2f(h[0]);
                a1 += w[1] * bf2f(h[1]);
                a2 += w[2] * bf2f(h[2]);
                a3 += w[3] * bf2f(h[3]);
            }
            for (; q < nj; q++) {
                const int o0 = __builtin_amdgcn_readlane(soff, q);
                const float w0 = __int_as_float(__builtin_amdgcn_readlane(wbits, q));
                const unsigned short h0 = *(const unsigned short*)(hbl + o0);
                a0 += w0 * bf2f(h0);
            }
            acc += ((a0 + a1) + (a2 + a3)) + ((a4 + a5) + (a6 + a7));
        }
        float o = acc / denom + bl;
        if (RELU) o = o > 0.f ? o : 0.f;
        if (OUTBF) ((unsigned short*)Out)[(size_t)i * 64 + lane] = f2bf(o);
        else       ((float*)Out)[(size_t)i * 64 + lane] = o;
    }
}

// ---------------- pooling (batch sorted; small chunks, many waves) ----------------

__global__ void pool_kernel(const float* __restrict__ H, const int* __restrict__ batch,
                            float* __restrict__ sums, int* __restrict__ cnts, int N) {
    const int CHUNK = 32;
    const int lane = threadIdx.x & 63;
    int gw = (blockIdx.x * blockDim.x + threadIdx.x) >> 6;
    const int nw = (gridDim.x * blockDim.x) >> 6;
    const int nchunks = (N + CHUNK - 1) / CHUNK;
    for (int c = gw; c < nchunks; c += nw) {
        const int lo = c * CHUNK;
        const int hi = min(lo + CHUNK, N);
        int curb = batch[lo];
        float acc = 0.f;
        int cnt = 0;
        for (int n = lo; n < hi; n++) {
            int b = batch[n];
            if (b != curb) {
                unsafeAtomicAdd(&sums[(size_t)curb * 64 + lane], acc);
                if (lane == 0) atomicAdd(&cnts[curb], cnt);
                acc = 0.f; cnt = 0; curb = b;
            }
            acc += H[(size_t)n * 64 + lane];
            cnt++;
        }
        unsafeAtomicAdd(&sums[(size_t)curb * 64 + lane], acc);
        if (lane == 0) atomicAdd(&cnts[curb], cnt);
    }
}

// ---------------- final MLP + log_softmax ----------------
__global__ void mlp_kernel(const float* __restrict__ sums, const int* __restrict__ cnts,
                           const float* __restrict__ lw, const float* __restrict__ lb,
                           const float* __restrict__ cw, const float* __restrict__ cb,
                           float* __restrict__ out) {
    __shared__ float gv[64];
    __shared__ float z[32];
    __shared__ float logits[6];
    const int g = blockIdx.x;
    const int t = threadIdx.x;

    float cnt = (float)cnts[g];
    cnt = cnt > 1.f ? cnt : 1.f;
    gv[t] = sums[(size_t)g * 64 + t] / cnt;
    __syncthreads();

    if (t < 32) {
        float acc = lb[t];
#pragma unroll
        for (int k = 0; k < 64; k++) acc += gv[k] * lw[k * 32 + t];
        z[t] = acc > 0.f ? acc : 0.f;
    }
    __syncthreads();
    if (t < 6) {
        float acc = cb[t];
#pragma unroll
        for (int k = 0; k < 32; k++) acc += z[k] * cw[k * 6 + t];
        logits[t] = acc;
    }
    __syncthreads();
    if (t == 0) {
        float m = logits[0];
#pragma unroll
        for (int i = 1; i < 6; i++) m = fmaxf(m, logits[i]);
        float s = 0.f;
#pragma unroll
        for (int i = 0; i < 6; i++) s += expf(logits[i] - m);
        float lse = m + logf(s);
#pragma unroll
        for (int i = 0; i < 6; i++) out[(size_t)g * 6 + i] = logits[i] - lse;
    }
}

// ---------------- launch ----------------

extern "C" void kernel_launch(void* const* d_in, const int* in_sizes, int n_in,
                              void* d_out, int out_size, void* d_ws, size_t ws_size,
                              hipStream_t stream) {
    const float* x    = (const float*)d_in[0];
    const int*   ei   = (const int*)d_in[1];
    const int*   batch= (const int*)d_in[2];
    const float* W1   = (const float*)d_in[3];
    const float* as1  = (const float*)d_in[4];
    const float* ad1  = (const float*)d_in[5];
    const float* b1   = (const float*)d_in[6];
    const float* W2   = (const float*)d_in[7];
    const float* as2  = (const float*)d_in[8];
    const float* ad2  = (const float*)d_in[9];
    const float* b2   = (const float*)d_in[10];
    const float* lw   = (const float*)d_in[11];
    const float* lb   = (const float*)d_in[12];
    const float* cw   = (const float*)d_in[13];
    const float* cb   = (const float*)d_in[14];
    float* out = (float*)d_out;

    const int N  = in_sizes[0] / 128;
    const int E  = in_sizes[1] / 2;
    const int G  = out_size / 6;
    const int NB = (N + BSZ - 1) / BSZ;

    char* ws = (char*)d_ws;
    size_t off = 0;
    auto alloc = [&](size_t bytes) {
        void* p = ws + off;
        off += (bytes + 255) & ~size_t(255);
        return p;
    };
    float*          hB     = (float*)alloc((size_t)N * 64 * 4);
    unsigned short* hB1b   = (unsigned short*)alloc((size_t)N * 64 * 2);
    unsigned short* Hb     = (unsigned short*)alloc((size_t)N * 64 * 2);
    float*          sc_s   = (float*)alloc((size_t)N * 4);
    float*          sc_d   = (float*)alloc((size_t)N * 4);
    int*            rowptr = (int*)alloc((size_t)(N + 1) * 4);
    int*            colidx = (int*)alloc((size_t)E * 4);
    unsigned*       staged = (unsigned*)alloc((size_t)E * 4);
    int*            bhist  = (int*)alloc((size_t)256 * 4);
    int*            bbase  = (int*)alloc((size_t)257 * 4);
    int*            bcur   = (int*)alloc((size_t)256 * 4);
    float*          psum   = (float*)alloc((size_t)G * 64 * 4);
    int*            pcnt   = (int*)alloc((size_t)G * 4);
    (void)ws_size;

    const int TB = 256;
    const int gemm_grid = (N + 63) / 64;
    const int part_blocks = (E + CH - 1) / CH;

    // ---- CSR build by dst ----
    hipMemsetAsync(bhist, 0, 256 * 4, stream);
    bucket_hist_kernel<<<1024, TB, 0, stream>>>(ei + E, bhist, E);
    bucket_scan_kernel<<<1, 256, 0, stream>>>(bhist, bbase, bcur, NB, E);
    partition_kernel<<<part_blocks, 256, 0, stream>>>(ei, E, bcur, staged);
    place_kernel<<<NB, 256, 0, stream>>>(staged, bbase, rowptr, colidx, N, E, NB);

    // ---- layer 1 ----
    gat_gemm_mfma<128, false><<<gemm_grid, TB, 0, stream>>>(x, W1, as1, ad1, Hb, sc_s, sc_d, N);
    gat_fused_agg<true, true><<<2048, TB, 0, stream>>>(rowptr, colidx, sc_s, sc_d, Hb, b1, hB1b, N);

    // ---- layer 2 ----
    gat_gemm_mfma<64, true><<<gemm_grid, TB, 0, stream>>>(hB1b, W2, as2, ad2, Hb, sc_s, sc_d, N);
    gat_fused_agg<false, false><<<2048, TB, 0, stream>>>(rowptr, colidx, sc_s, sc_d, Hb, b2, hB, N);

    // ---- pooling + MLP head ----
    hipMemsetAsync(psum, 0, (size_t)G * 64 * 4, stream);
    hipMemsetAsync(pcnt, 0, (size_t)G * 4, stream);
    pool_kernel<<<1024, TB, 0, stream>>>(hB, batch, psum, pcnt, N);
    mlp_kernel<<<G, 64, 0, stream>>>(psum, pcnt, lw, lb, cw, cb, out);
}

// Round 14
// 322.565 us; speedup vs baseline: 2.4008x; 1.1596x over previous
//
#include <hip/hip_runtime.h>

// ---------------- bf16 helpers ----------------

__device__ __forceinline__ unsigned short f2bf(float f) {
    unsigned u = __float_as_uint(f);
    unsigned r = (u + 0x7FFFu + ((u >> 16) & 1u)) >> 16;
    return (unsigned short)r;
}
__device__ __forceinline__ float bf2f(unsigned short u) {
    return __uint_as_float(((unsigned)u) << 16);
}

typedef __attribute__((ext_vector_type(8))) short bf16x8;
typedef __attribute__((ext_vector_type(4))) float f32x4;
typedef __attribute__((ext_vector_type(8))) unsigned short u16x8;

// ---------------- node GEMM via MFMA + attention scores ----------------
template<int K, bool IN_BF16>
__global__ __launch_bounds__(256, 4)
void gat_gemm_mfma(const void* __restrict__ Xin, const float* __restrict__ W,
                   const float* __restrict__ a_s, const float* __restrict__ a_d,
                   unsigned short* __restrict__ Hb, float* __restrict__ sc_s,
                   float* __restrict__ sc_d, int nrows) {
    __shared__ unsigned short Xl[64 * K];
    __shared__ unsigned short Wt[K * 64];
    const int t = threadIdx.x;
    const int tile0 = blockIdx.x * 64;
    const int CPR = K / 8;

    for (int c = t; c < 64 * CPR; c += 256) {
        const int row = c / CPR;
        const int ch  = c % CPR;
        const int gr  = tile0 + row;
        u16x8 v;
        if (gr < nrows) {
            if (IN_BF16) {
                v = *reinterpret_cast<const u16x8*>((const unsigned short*)Xin + (size_t)gr * K + ch * 8);
            } else {
                const float* src = (const float*)Xin + (size_t)gr * K + ch * 8;
                const float4 f0 = *reinterpret_cast<const float4*>(src);
                const float4 f1 = *reinterpret_cast<const float4*>(src + 4);
                v[0] = f2bf(f0.x); v[1] = f2bf(f0.y); v[2] = f2bf(f0.z); v[3] = f2bf(f0.w);
                v[4] = f2bf(f1.x); v[5] = f2bf(f1.y); v[6] = f2bf(f1.z); v[7] = f2bf(f1.w);
            }
        } else {
#pragma unroll
            for (int i = 0; i < 8; i++) v[i] = 0;
        }
        *reinterpret_cast<u16x8*>(&Xl[row * K + ((ch * 8) ^ ((row & 7) << 3))]) = v;
    }
    for (int i = t; i < K * 64; i += 256) {
        const int k = i >> 6;
        const int n = i & 63;
        Wt[((k >> 3) * 64 + n) * 8 + (k & 7)] = f2bf(W[i]);
    }
    __syncthreads();

    const int lane = t & 63;
    const int wave = t >> 6;
    const int lg = lane >> 4;
    const int li = lane & 15;

    f32x4 acc[4] = {{0.f,0.f,0.f,0.f},{0.f,0.f,0.f,0.f},{0.f,0.f,0.f,0.f},{0.f,0.f,0.f,0.f}};
    const int r = wave * 16 + li;

#pragma unroll
    for (int s = 0; s < K / 32; s++) {
        const int acol = (s * 32 + lg * 8) ^ ((r & 7) << 3);
        const bf16x8 a = *reinterpret_cast<const bf16x8*>(&Xl[r * K + acol]);
#pragma unroll
        for (int ct = 0; ct < 4; ct++) {
            const bf16x8 b = *reinterpret_cast<const bf16x8*>(&Wt[((s * 4 + lg) * 64 + ct * 16 + li) * 8]);
            acc[ct] = __builtin_amdgcn_mfma_f32_16x16x32_bf16(a, b, acc[ct], 0, 0, 0);
        }
    }

    float asv[4], adv[4];
#pragma unroll
    for (int ct = 0; ct < 4; ct++) {
        asv[ct] = a_s[ct * 16 + li];
        adv[ct] = a_d[ct * 16 + li];
    }
#pragma unroll
    for (int reg = 0; reg < 4; reg++) {
        const int gr = tile0 + wave * 16 + lg * 4 + reg;
        float ps = 0.f, pd = 0.f;
        if (gr < nrows) {
#pragma unroll
            for (int ct = 0; ct < 4; ct++) {
                const float v = acc[ct][reg];
                Hb[(size_t)gr * 64 + ct * 16 + li] = f2bf(v);
                ps += v * asv[ct];
                pd += v * adv[ct];
            }
        }
#pragma unroll
        for (int off = 8; off; off >>= 1) {
            ps += __shfl_xor(ps, off);
            pd += __shfl_xor(pd, off);
        }
        if (li == 0 && gr < nrows) {
            sc_s[gr] = ps;
            sc_d[gr] = pd;
        }
    }
}

// ---------------- CSR build: bucket hist -> bucket scan -> partition -> place
#define BSZ   512
#define NBITS 9
#define CH    4096

__global__ __launch_bounds__(256)
void bucket_hist_kernel(const int* __restrict__ dst, int* __restrict__ bhist, int E) {
    __shared__ int cnt[256];
    const int t = threadIdx.x;
    cnt[t] = 0;
    __syncthreads();
    const int tid = blockIdx.x * blockDim.x + t;
    const int stride = gridDim.x * blockDim.x;
    const int E4 = E >> 2;
    for (int i = tid; i < E4; i += stride) {
        const int4 d = reinterpret_cast<const int4*>(dst)[i];
        atomicAdd(&cnt[d.x >> NBITS], 1);
        atomicAdd(&cnt[d.y >> NBITS], 1);
        atomicAdd(&cnt[d.z >> NBITS], 1);
        atomicAdd(&cnt[d.w >> NBITS], 1);
    }
    for (int i = (E4 << 2) + tid; i < E; i += stride)
        atomicAdd(&cnt[dst[i] >> NBITS], 1);
    __syncthreads();
    if (cnt[t] > 0) atomicAdd(&bhist[t], cnt[t]);
}

__global__ void bucket_scan_kernel(const int* __restrict__ bhist, int* __restrict__ bbase,
                                   int* __restrict__ bcur, int NB, int E) {
    __shared__ int s[256];
    const int t = threadIdx.x;
    const int v = (t < NB) ? bhist[t] : 0;
    s[t] = v;
    __syncthreads();
    for (int off = 1; off < 256; off <<= 1) {
        int u = (t >= off) ? s[t - off] : 0;
        __syncthreads();
        s[t] += u;
        __syncthreads();
    }
    if (t < NB) {
        const int excl = s[t] - v;
        bbase[t] = excl;
        bcur[t] = excl;
    }
    if (t == 0) bbase[NB] = E;
}

__global__ __launch_bounds__(256)
void partition_kernel(const int* __restrict__ ei, int E,
                      int* __restrict__ bcur, unsigned* __restrict__ staged) {
    __shared__ int cnt[256], scantmp[256], excl[256], cnt2[256], gbase[256];
    __shared__ unsigned packed[CH];
    __shared__ unsigned char bid[CH];
    const int t = threadIdx.x;
    const int e0 = blockIdx.x * CH;

    cnt[t] = 0;
    cnt2[t] = 0;
    __syncthreads();

    unsigned pk[16];
    int bb[16];
#pragma unroll
    for (int i = 0; i < 16; i++) {
        const int e = e0 + i * 256 + t;
        if (e < E) {
            const int d = ei[E + e];
            const int s = ei[e];
            bb[i] = d >> NBITS;
            pk[i] = ((unsigned)(d & (BSZ - 1)) << 17) | (unsigned)s;
            atomicAdd(&cnt[bb[i]], 1);
        } else bb[i] = -1;
    }
    __syncthreads();

    int v = cnt[t];
    scantmp[t] = v;
    __syncthreads();
    for (int off = 1; off < 256; off <<= 1) {
        int u = (t >= off) ? scantmp[t - off] : 0;
        __syncthreads();
        scantmp[t] += u;
        __syncthreads();
    }
    excl[t] = scantmp[t] - v;
    if (v > 0) gbase[t] = atomicAdd(&bcur[t], v);
    __syncthreads();

#pragma unroll
    for (int i = 0; i < 16; i++) {
        if (bb[i] >= 0) {
            const int slot = atomicAdd(&cnt2[bb[i]], 1);
            const int p = excl[bb[i]] + slot;
            packed[p] = pk[i];
            bid[p] = (unsigned char)bb[i];
        }
    }
    __syncthreads();

    const int nvalid = min(CH, E - e0);
    for (int i = t; i < nvalid; i += 256) {
        const int b = bid[i];
        staged[gbase[b] + (i - excl[b])] = packed[i];
    }
}

__global__ __launch_bounds__(256)
void place_kernel(const unsigned* __restrict__ staged, const int* __restrict__ bbase,
                  int* __restrict__ rowptr, int* __restrict__ col, int N, int E, int NB) {
    __shared__ int nc[BSZ];
    __shared__ int rp[BSZ];
    __shared__ int pairs[256];
    const int b = blockIdx.x;
    const int n0 = b * BSZ;
    const int nn = min(BSZ, N - n0);
    const int t = threadIdx.x;

    nc[t] = 0;
    nc[t + 256] = 0;
    __syncthreads();

    const int lo = bbase[b];
    const int hi = bbase[b + 1];
    for (int e = lo + t; e < hi; e += 256)
        atomicAdd(&nc[staged[e] >> 17], 1);
    __syncthreads();

    const int c0 = nc[2 * t], c1 = nc[2 * t + 1];
    const int ps = c0 + c1;
    pairs[t] = ps;
    __syncthreads();
    for (int off = 1; off < 256; off <<= 1) {
        int u = (t >= off) ? pairs[t - off] : 0;
        __syncthreads();
        pairs[t] += u;
        __syncthreads();
    }
    const int pexcl = pairs[t] - ps;
    rp[2 * t]     = lo + pexcl;
    rp[2 * t + 1] = lo + pexcl + c0;
    nc[2 * t] = 0;
    nc[2 * t + 1] = 0;
    __syncthreads();

    for (int i = t; i < nn; i += 256) rowptr[n0 + i] = rp[i];
    if (b == NB - 1 && t == 0) rowptr[N] = E;

    for (int e = lo + t; e < hi; e += 256) {
        const unsigned p = staged[e];
        const int dlo = (int)(p >> 17);
        const int src = (int)(p & 0x1FFFFu);
        const int pos = rp[dlo] + atomicAdd(&nc[dlo], 1);
        col[pos] = src;
    }
}

// ---------------- fused per-node online-softmax aggregation ------------------
// Wave-parallel softmax; TWO nodes per wave with staggered chunk pipelines:
// both nodes' per-lane gathers issue before either node's compute, so node-1
// gather latency hides under node-0 softmax/broadcast. Branches wave-uniform.
template<bool RELU, bool OUTBF>
__global__ void gat_fused_agg(const int* __restrict__ rowptr, const int* __restrict__ col,
                              const float* __restrict__ sc_s, const float* __restrict__ sc_d,
                              const unsigned short* __restrict__ Hb, const float* __restrict__ bias,
                              void* __restrict__ Out, int N) {
    const int lane = threadIdx.x & 63;
    int gw = (blockIdx.x * blockDim.x + threadIdx.x) >> 6;
    const int nw = (gridDim.x * blockDim.x) >> 6;
    const float bl = bias[lane];
    const char* hbl = (const char*)Hb + lane * 2;
    const int npairs = (N + 1) >> 1;

    // phase-2: 4 independent broadcast-load chains; returns contribution
    auto phase2 = [&](int nj, int soff, float wl) -> float {
        const int wbits = __float_as_int(wl);
        float a0 = 0.f, a1 = 0.f, a2 = 0.f, a3 = 0.f;
        int q = 0;
        for (; q + 4 <= nj; q += 4) {
            const int o0 = __builtin_amdgcn_readlane(soff, q);
            const int o1 = __builtin_amdgcn_readlane(soff, q + 1);
            const int o2 = __builtin_amdgcn_readlane(soff, q + 2);
            const int o3 = __builtin_amdgcn_readlane(soff, q + 3);
            const float w0 = __int_as_float(__builtin_amdgcn_readlane(wbits, q));
            const float w1 = __int_as_float(__builtin_amdgcn_readlane(wbits, q + 1));
            const float w2 = __int_as_float(__builtin_amdgcn_readlane(wbits, q + 2));
            const float w3 = __int_as_float(__builtin_amdgcn_readlane(wbits, q + 3));
            const unsigned short h0 = *(const unsigned short*)(hbl + o0);
            const unsigned short h1 = *(const unsigned short*)(hbl + o1);
            const unsigned short h2 = *(const unsigned short*)(hbl + o2);
            const unsigned short h3 = *(const unsigned short*)(hbl + o3);
            a0 += w0 * bf2f(h0);
            a1 += w1 * bf2f(h1);
            a2 += w2 * bf2f(h2);
            a3 += w3 * bf2f(h3);
        }
        for (; q < nj; q++) {
            const int o0 = __builtin_amdgcn_readlane(soff, q);
            const float w0 = __int_as_float(__builtin_amdgcn_readlane(wbits, q));
            const unsigned short h0 = *(const unsigned short*)(hbl + o0);
            a0 += w0 * bf2f(h0);
        }
        return (a0 + a1) + (a2 + a3);
    };

    for (int p = gw; p < npairs; p += nw) {
        const int i0 = 2 * p;
        const int i1 = 2 * p + 1;
        const bool has1 = (i1 < N);

        const float scd0 = sc_d[i0];
        float es0 = sc_s[i0] + scd0;
        es0 = es0 > 0.f ? es0 : 0.2f * es0;
        float m0 = es0, denom0 = 1.f;
        float acc0 = bf2f(Hb[(size_t)i0 * 64 + lane]);
        int j0 = rowptr[i0];
        const int je0 = rowptr[i0 + 1];

        float scd1 = 0.f, m1 = 0.f, denom1 = 1.f, acc1 = 0.f;
        int j1 = 0, je1 = 0;
        if (has1) {
            scd1 = sc_d[i1];
            float es1 = sc_s[i1] + scd1;
            es1 = es1 > 0.f ? es1 : 0.2f * es1;
            m1 = es1;
            acc1 = bf2f(Hb[(size_t)i1 * 64 + lane]);
            j1 = rowptr[i1];
            je1 = rowptr[i1 + 1];
        }

        while (j0 < je0 || j1 < je1) {
            // ---- issue BOTH nodes' per-lane gathers first ----
            int nj0 = 0, nj1 = 0;
            int soff0 = 0, soff1 = 0;
            float el0 = -1e30f, el1 = -1e30f;
            if (j0 < je0) {
                nj0 = min(64, je0 - j0);
                if (lane < nj0) {
                    const int sl = col[j0 + lane];
                    soff0 = sl << 7;
                    const float ev = sc_s[sl] + scd0;
                    el0 = ev > 0.f ? ev : 0.2f * ev;
                }
            }
            if (j1 < je1) {
                nj1 = min(64, je1 - j1);
                if (lane < nj1) {
                    const int sl = col[j1 + lane];
                    soff1 = sl << 7;
                    const float ev = sc_s[sl] + scd1;
                    el1 = ev > 0.f ? ev : 0.2f * ev;
                }
            }
            // ---- node 0: softmax + broadcast accumulate ----
            if (nj0) {
                float cm = el0;
#pragma unroll
                for (int off = 32; off; off >>= 1) cm = fmaxf(cm, __shfl_xor(cm, off));
                const float mn = fmaxf(m0, cm);
                float wl = (lane < nj0) ? __expf(el0 - mn) : 0.f;
                float wsum = wl;
#pragma unroll
                for (int off = 32; off; off >>= 1) wsum += __shfl_xor(wsum, off);
                const float scale = __expf(m0 - mn);
                denom0 = denom0 * scale + wsum;
                acc0 = acc0 * scale + phase2(nj0, soff0, wl);
                m0 = mn;
                j0 += 64;
            }
            // ---- node 1 ----
            if (nj1) {
                float cm = el1;
#pragma unroll
                for (int off = 32; off; off >>= 1) cm = fmaxf(cm, __shfl_xor(cm, off));
                const float mn = fmaxf(m1, cm);
                float wl = (lane < nj1) ? __expf(el1 - mn) : 0.f;
                float wsum = wl;
#pragma unroll
                for (int off = 32; off; off >>= 1) wsum += __shfl_xor(wsum, off);
                const float scale = __expf(m1 - mn);
                denom1 = denom1 * scale + wsum;
                acc1 = acc1 * scale + phase2(nj1, soff1, wl);
                m1 = mn;
                j1 += 64;
            }
        }

        {
            float o = acc0 / denom0 + bl;
            if (RELU) o = o > 0.f ? o : 0.f;
            if (OUTBF) ((unsigned short*)Out)[(size_t)i0 * 64 + lane] = f2bf(o);
            else       ((float*)Out)[(size_t)i0 * 64 + lane] = o;
        }
        if (has1) {
            float o = acc1 / denom1 + bl;
            if (RELU) o = o > 0.f ? o : 0.f;
            if (OUTBF) ((unsigned short*)Out)[(size_t)i1 * 64 + lane] = f2bf(o);
            else       ((float*)Out)[(size_t)i1 * 64 + lane] = o;
        }
    }
}

// ---------------- pooling (batch sorted; small chunks, many waves) ----------------

__global__ void pool_kernel(const float* __restrict__ H, const int* __restrict__ batch,
                            float* __restrict__ sums, int* __restrict__ cnts, int N) {
    const int CHUNK = 32;
    const int lane = threadIdx.x & 63;
    int gw = (blockIdx.x * blockDim.x + threadIdx.x) >> 6;
    const int nw = (gridDim.x * blockDim.x) >> 6;
    const int nchunks = (N + CHUNK - 1) / CHUNK;
    for (int c = gw; c < nchunks; c += nw) {
        const int lo = c * CHUNK;
        const int hi = min(lo + CHUNK, N);
        int curb = batch[lo];
        float acc = 0.f;
        int cnt = 0;
        for (int n = lo; n < hi; n++) {
            int b = batch[n];
            if (b != curb) {
                unsafeAtomicAdd(&sums[(size_t)curb * 64 + lane], acc);
                if (lane == 0) atomicAdd(&cnts[curb], cnt);
                acc = 0.f; cnt = 0; curb = b;
            }
            acc += H[(size_t)n * 64 + lane];
            cnt++;
        }
        unsafeAtomicAdd(&sums[(size_t)curb * 64 + lane], acc);
        if (lane == 0) atomicAdd(&cnts[curb], cnt);
    }
}

// ---------------- final MLP + log_softmax ----------------
__global__ void mlp_kernel(const float* __restrict__ sums, const int* __restrict__ cnts,
                           const float* __restrict__ lw, const float* __restrict__ lb,
                           const float* __restrict__ cw, const float* __restrict__ cb,
                           float* __restrict__ out) {
    __shared__ float gv[64];
    __shared__ float z[32];
    __shared__ float logits[6];
    const int g = blockIdx.x;
    const int t = threadIdx.x;

    float cnt = (float)cnts[g];
    cnt = cnt > 1.f ? cnt : 1.f;
    gv[t] = sums[(size_t)g * 64 + t] / cnt;
    __syncthreads();

    if (t < 32) {
        float acc = lb[t];
#pragma unroll
        for (int k = 0; k < 64; k++) acc += gv[k] * lw[k * 32 + t];
        z[t] = acc > 0.f ? acc : 0.f;
    }
    __syncthreads();
    if (t < 6) {
        float acc = cb[t];
#pragma unroll
        for (int k = 0; k < 32; k++) acc += z[k] * cw[k * 6 + t];
        logits[t] = acc;
    }
    __syncthreads();
    if (t == 0) {
        float m = logits[0];
#pragma unroll
        for (int i = 1; i < 6; i++) m = fmaxf(m, logits[i]);
        float s = 0.f;
#pragma unroll
        for (int i = 0; i < 6; i++) s += expf(logits[i] - m);
        float lse = m + logf(s);
#pragma unroll
        for (int i = 0; i < 6; i++) out[(size_t)g * 6 + i] = logits[i] - lse;
    }
}

// ---------------- launch ----------------

extern "C" void kernel_launch(void* const* d_in, const int* in_sizes, int n_in,
                              void* d_out, int out_size, void* d_ws, size_t ws_size,
                              hipStream_t stream) {
    const float* x    = (const float*)d_in[0];
    const int*   ei   = (const int*)d_in[1];
    const int*   batch= (const int*)d_in[2];
    const float* W1   = (const float*)d_in[3];
    const float* as1  = (const float*)d_in[4];
    const float* ad1  = (const float*)d_in[5];
    const float* b1   = (const float*)d_in[6];
    const float* W2   = (const float*)d_in[7];
    const float* as2  = (const float*)d_in[8];
    const float* ad2  = (const float*)d_in[9];
    const float* b2   = (const float*)d_in[10];
    const float* lw   = (const float*)d_in[11];
    const float* lb   = (const float*)d_in[12];
    const float* cw   = (const float*)d_in[13];
    const float* cb   = (const float*)d_in[14];
    float* out = (float*)d_out;

    const int N  = in_sizes[0] / 128;
    const int E  = in_sizes[1] / 2;
    const int G  = out_size / 6;
    const int NB = (N + BSZ - 1) / BSZ;

    char* ws = (char*)d_ws;
    size_t off = 0;
    auto alloc = [&](size_t bytes) {
        void* p = ws + off;
        off += (bytes + 255) & ~size_t(255);
        return p;
    };
    float*          hB     = (float*)alloc((size_t)N * 64 * 4);
    unsigned short* hB1b   = (unsigned short*)alloc((size_t)N * 64 * 2);
    unsigned short* Hb     = (unsigned short*)alloc((size_t)N * 64 * 2);
    float*          sc_s   = (float*)alloc((size_t)N * 4);
    float*          sc_d   = (float*)alloc((size_t)N * 4);
    int*            rowptr = (int*)alloc((size_t)(N + 1) * 4);
    int*            colidx = (int*)alloc((size_t)E * 4);
    unsigned*       staged = (unsigned*)alloc((size_t)E * 4);
    int*            bhist  = (int*)alloc((size_t)256 * 4);
    int*            bbase  = (int*)alloc((size_t)257 * 4);
    int*            bcur   = (int*)alloc((size_t)256 * 4);
    float*          psum   = (float*)alloc((size_t)G * 64 * 4);
    int*            pcnt   = (int*)alloc((size_t)G * 4);
    (void)ws_size;

    const int TB = 256;
    const int gemm_grid = (N + 63) / 64;
    const int part_blocks = (E + CH - 1) / CH;

    // ---- CSR build by dst ----
    hipMemsetAsync(bhist, 0, 256 * 4, stream);
    bucket_hist_kernel<<<1024, TB, 0, stream>>>(ei + E, bhist, E);
    bucket_scan_kernel<<<1, 256, 0, stream>>>(bhist, bbase, bcur, NB, E);
    partition_kernel<<<part_blocks, 256, 0, stream>>>(ei, E, bcur, staged);
    place_kernel<<<NB, 256, 0, stream>>>(staged, bbase, rowptr, colidx, N, E, NB);

    // ---- layer 1 ----
    gat_gemm_mfma<128, false><<<gemm_grid, TB, 0, stream>>>(x, W1, as1, ad1, Hb, sc_s, sc_d, N);
    gat_fused_agg<true, true><<<2048, TB, 0, stream>>>(rowptr, colidx, sc_s, sc_d, Hb, b1, hB1b, N);

    // ---- layer 2 ----
    gat_gemm_mfma<64, true><<<gemm_grid, TB, 0, stream>>>(hB1b, W2, as2, ad2, Hb, sc_s, sc_d, N);
    gat_fused_agg<false, false><<<2048, TB, 0, stream>>>(rowptr, colidx, sc_s, sc_d, Hb, b2, hB, N);

    // ---- pooling + MLP head ----
    hipMemsetAsync(psum, 0, (size_t)G * 64 * 4, stream);
    hipMemsetAsync(pcnt, 0, (size_t)G * 4, stream);
    pool_kernel<<<1024, TB, 0, stream>>>(hB, batch, psum, pcnt, N);
    mlp_kernel<<<G, 64, 0, stream>>>(psum, pcnt, lw, lb, cw, cb, out);
}